// Round 14
// baseline (1713.793 us; speedup 1.0000x reference)
//
#include <hip/hip_runtime.h>
#include <math.h>

// ---------------- model constants ----------------
#define S_LEN 1024
#define HIDN  2048
#define NVH   16      // NV heads (delta v)
#define CDIM  4096    // conv dim
#define MAXKV 4096
#define SP    512
#define LMN   32000
// attention: NQ=16 heads, NKV=2, HD=128

typedef __attribute__((ext_vector_type(4))) float f32x4v;
typedef _Float16 f16x8 __attribute__((ext_vector_type(8)));
typedef unsigned short ushort_t;

// fp16 pre-swizzled lm_head weight image (rewritten every call)
__device__ ushort_t g_LM16[65536000ULL];   // (2048/32)*4096 per 128-col panel * 250

// f32 pair -> packed fp16 (RTZ, single v_cvt_pkrtz_f16_f32)
__device__ __forceinline__ unsigned int pack2h(float a, float b) {
  auto h = __builtin_amdgcn_cvt_pkrtz(a, b);   // __fp16 ext_vector(2)
  return __builtin_bit_cast(unsigned int, h);
}
__device__ __forceinline__ ushort_t h16(float x) {
  auto v = __builtin_amdgcn_cvt_pkrtz(x, x);
  return (ushort_t)__builtin_bit_cast(unsigned int, v);
}
// async global->LDS, 16B per lane; LDS dest = wave-uniform base + lane*16
__device__ __forceinline__ void gload16(const void* g, void* l) {
  __builtin_amdgcn_global_load_lds(
      (const __attribute__((address_space(1))) void*)(g),
      (__attribute__((address_space(3))) void*)(l), 16, 0, 0);
}

// =================================================================
// convw_lm: lm_head_w f32 [2048][32000] -> g_LM16 fp16 tiles
// tile layout per (npanel, ktile): [kb(4)][n(128)][j(8)] = 4096 ushorts
// thread: 8 consecutive k x 1 n -> one uint4 (read & write coalesced)
// =================================================================
__global__ __launch_bounds__(256) void convw_lm(const float* __restrict__ W) {
  int t = blockIdx.x * 256 + threadIdx.x;   // (2048/8)*32000 = 8,192,000
  int n_glob = t % LMN;
  int kb_glob = t / LMN;
  int kt = kb_glob >> 2, kb = kb_glob & 3;
  int np = n_glob >> 7, n = n_glob & 127;
  const float* src = W + (size_t)(kt * 32 + kb * 8) * LMN + n_glob;
  float v0 = src[0];
  float v1 = src[(size_t)LMN];
  float v2 = src[(size_t)2 * LMN];
  float v3 = src[(size_t)3 * LMN];
  float v4 = src[(size_t)4 * LMN];
  float v5 = src[(size_t)5 * LMN];
  float v6 = src[(size_t)6 * LMN];
  float v7 = src[(size_t)7 * LMN];
  *(uint4*)(g_LM16 + ((size_t)np * 64 + kt) * 4096 + (size_t)((kb << 7) + n) * 8)
      = make_uint4(pack2h(v0, v1), pack2h(v2, v3), pack2h(v4, v5), pack2h(v6, v7));
}

// =================================================================
// gemm_hh: BOTH operands fp16 pre-swizzled, staged via global_load_lds
// (m97 structure: zero staging VALU/registers). TM=128, BK=32, 4 waves.
// A image [mp64][kt][kb(4)][m(64)][j(8)]; B image [np128][kt][kb(4)][n(128)][j(8)].
// =================================================================
__global__ __launch_bounds__(256) void gemm_hh(const ushort_t* __restrict__ A16,
    const ushort_t* __restrict__ B16, float* __restrict__ C, int M, int N, int K) {
  __shared__ ushort_t Al[4096];   // [kb][128][8]  8KB (gload dest)
  __shared__ ushort_t Bl[4096];   // [kb][128][8]  8KB (gload dest)
  const int tid = threadIdx.x;
  const int gm = M >> 7;
  const int nwg = gridDim.x;
  const int q = nwg >> 3, r = nwg & 7;
  const int xcd = blockIdx.x & 7, ii = blockIdx.x >> 3;
  const int lin = (xcd < r) ? (xcd * (q + 1) + ii)
                            : (r * (q + 1) + (xcd - r) * q + ii);
  const int m0 = (lin % gm) * 128;
  const int n0 = (lin / gm) * 128;
  const int wave = tid >> 6, lane = tid & 63;
  const int wm = (wave >> 1) * 64, wn = (wave & 1) * 64;
  const int lr = lane & 15, lg = lane >> 4;
  const int NT = K >> 5;
  const size_t panA = (size_t)NT * 2048;          // ushorts per 64-row A panel
  const ushort_t* ApanL = A16 + (size_t)(m0 >> 6) * panA;
  const ushort_t* ApanH = ApanL + panA;
  const ushort_t* Bpan = B16 + (size_t)(n0 >> 7) * NT * 4096;
  f32x4v acc[4][4];
  #pragma unroll
  for (int i = 0; i < 4; ++i)
    #pragma unroll
    for (int j = 0; j < 4; ++j)
      #pragma unroll
      for (int r2 = 0; r2 < 4; ++r2) acc[i][j][r2] = 0.f;
  for (int t = 0; t < NT; ++t) {
    __syncthreads();   // previous tile's consumers done
    // A: 8 chunks of 1KB (2/wave); chunk c: kb=c>>1, half=c&1
    #pragma unroll
    for (int i2 = 0; i2 < 2; ++i2) {
      int c = wave * 2 + i2;
      int kb = c >> 1, hf = c & 1;
      gload16((hf ? ApanH : ApanL) + (size_t)t * 2048 + kb * 512 + lane * 8,
              Al + kb * 1024 + hf * 512);
    }
    // B: 8 chunks of 1KB (2/wave); layout linear-identical src->dst
    #pragma unroll
    for (int i2 = 0; i2 < 2; ++i2) {
      int c = wave * 2 + i2;
      gload16(Bpan + (size_t)t * 4096 + c * 512 + lane * 8, Bl + c * 512);
    }
    __syncthreads();   // drains vmcnt: both tiles landed
    f16x8 af[4], bfr[4];
    #pragma unroll
    for (int mi = 0; mi < 4; ++mi)
      af[mi] = *(const f16x8*)&Al[lg * 1024 + (wm + mi * 16 + lr) * 8];
    #pragma unroll
    for (int ni = 0; ni < 4; ++ni)
      bfr[ni] = *(const f16x8*)&Bl[lg * 1024 + (wn + ni * 16 + lr) * 8];
    #pragma unroll
    for (int mi = 0; mi < 4; ++mi)
      #pragma unroll
      for (int ni = 0; ni < 4; ++ni)
        acc[mi][ni] = __builtin_amdgcn_mfma_f32_16x16x32_f16(
            af[mi], bfr[ni], acc[mi][ni], 0, 0, 0);
  }
  #pragma unroll
  for (int mi = 0; mi < 4; ++mi) {
    #pragma unroll
    for (int ni = 0; ni < 4; ++ni) {
      const int rr = m0 + wm + mi * 16 + lg * 4;
      const int cc = n0 + wn + ni * 16 + lr;
      #pragma unroll
      for (int r2 = 0; r2 < 4; ++r2)
        C[(size_t)(rr + r2) * N + cc] = acc[mi][ni][r2];
    }
  }
}

// =================================================================
// gemm_h: A fp16 pre-swizzled via gload; B f32 reg-converted.
// =================================================================
template<int TM, bool ACC>
__global__ __launch_bounds__(256) void gemm_h(const ushort_t* __restrict__ A16,
    const float* __restrict__ B, float* __restrict__ C, int M, int N, int K) {
  constexpr int MI = TM / 32;
  __shared__ ushort_t Al[TM * 32];
  __shared__ unsigned int Bl[4][128][4];
  const int tid = threadIdx.x;
  const int gm = M / TM;
  const int nwg = gridDim.x;
  const int q = nwg >> 3, r = nwg & 7;
  const int xcd = blockIdx.x & 7, ii = blockIdx.x >> 3;
  const int lin = (xcd < r) ? (xcd * (q + 1) + ii)
                            : (r * (q + 1) + (xcd - r) * q + ii);
  const int m0 = (lin % gm) * TM;
  const int n0 = (lin / gm) * 128;
  const int wave = tid >> 6, lane = tid & 63;
  const int wm = (wave >> 1) * (TM / 2), wn = (wave & 1) * 64;
  const int lr = lane & 15, lg = lane >> 4;
  const int bn = tid & 127, bkb = (tid >> 7) * 2;
  const size_t panstride = (size_t)(K >> 5) * 2048;
  const ushort_t* Apan = A16 + (size_t)(m0 >> 6) * panstride;
  const float* Bp = B + (size_t)(bkb * 8) * N + n0 + bn;
  float br[16];
  f32x4v acc[MI][4];
  #pragma unroll
  for (int i = 0; i < MI; ++i)
    #pragma unroll
    for (int j = 0; j < 4; ++j)
      #pragma unroll
      for (int r2 = 0; r2 < 4; ++r2) acc[i][j][r2] = 0.f;
  const int NT = K >> 5;
  #pragma unroll
  for (int j = 0; j < 16; ++j) br[j] = Bp[(size_t)j * N];
  for (int t = 0; t < NT; ++t) {
    __syncthreads();
    if (TM == 128) {
      #pragma unroll
      for (int i2 = 0; i2 < 2; ++i2) {
        int c = wave * 2 + i2;
        int kb = c >> 1, half = c & 1;
        gload16(Apan + half * panstride + (size_t)t * 2048 + kb * 512 + lane * 8,
                Al + kb * 1024 + half * 512);
      }
    } else {
      int kb = wave;
      gload16(Apan + (size_t)t * 2048 + kb * 512 + lane * 8, Al + kb * 512);
    }
    *(uint4*)&Bl[bkb][bn][0] = make_uint4(
        pack2h(br[0], br[1]), pack2h(br[2], br[3]),
        pack2h(br[4], br[5]), pack2h(br[6], br[7]));
    *(uint4*)&Bl[bkb + 1][bn][0] = make_uint4(
        pack2h(br[8], br[9]), pack2h(br[10], br[11]),
        pack2h(br[12], br[13]), pack2h(br[14], br[15]));
    if (t + 1 < NT) {
      Bp += (size_t)32 * N;
      #pragma unroll
      for (int j = 0; j < 16; ++j) br[j] = Bp[(size_t)j * N];
    }
    __syncthreads();
    f16x8 af[MI], bfr[4];
    #pragma unroll
    for (int mi = 0; mi < MI; ++mi)
      af[mi] = *(const f16x8*)&Al[lg * (TM * 8) + (wm + mi * 16 + lr) * 8];
    #pragma unroll
    for (int ni = 0; ni < 4; ++ni)
      bfr[ni] = *(const f16x8*)&Bl[lg][wn + ni * 16 + lr][0];
    #pragma unroll
    for (int mi = 0; mi < MI; ++mi)
      #pragma unroll
      for (int ni = 0; ni < 4; ++ni)
        acc[mi][ni] = __builtin_amdgcn_mfma_f32_16x16x32_f16(
            af[mi], bfr[ni], acc[mi][ni], 0, 0, 0);
  }
  #pragma unroll
  for (int mi = 0; mi < MI; ++mi) {
    #pragma unroll
    for (int ni = 0; ni < 4; ++ni) {
      const int rr = m0 + wm + mi * 16 + lg * 4;
      const int cc = n0 + wn + ni * 16 + lr;
      #pragma unroll
      for (int r2 = 0; r2 < 4; ++r2) {
        float* cp = C + (size_t)(rr + r2) * N + cc;
        if (ACC) *cp += acc[mi][ni][r2];
        else     *cp = acc[mi][ni][r2];
      }
    }
  }
}

// =================================================================
// gemm_f16: both operands f32, reg-converted (ACC / fused-silu cases)
// =================================================================
template<int TM, bool ACC, bool FS>
__global__ __launch_bounds__(256) void gemm_f16(const float* __restrict__ A,
    const float* A2, const float* __restrict__ B,
    float* __restrict__ C, int M, int N, int K) {
  constexpr int MI = TM / 32;
  constexpr int AF = TM / 8;
  __shared__ unsigned int Al[4][TM][4];
  __shared__ unsigned int Bl[4][128][4];
  const int tid = threadIdx.x;
  const int gm = M / TM;
  const int nwg = gridDim.x;
  const int q = nwg >> 3, r = nwg & 7;
  const int xcd = blockIdx.x & 7, ii = blockIdx.x >> 3;
  const int lin = (xcd < r) ? (xcd * (q + 1) + ii)
                            : (r * (q + 1) + (xcd - r) * q + ii);
  const int m0 = (lin % gm) * TM;
  const int n0 = (lin / gm) * 128;
  const int wave = tid >> 6, lane = tid & 63;
  const int wm = (wave >> 1) * (TM / 2), wn = (wave & 1) * 64;
  const int lr = lane & 15, lg = lane >> 4;
  const int am  = (TM == 128) ? (tid >> 1) : (tid >> 2);
  const int akb = (TM == 128) ? ((tid & 1) * 2) : (tid & 3);
  const int bn = tid & 127, bkb = (tid >> 7) * 2;
  const float* Ap  = A + (size_t)(m0 + am) * K + akb * 8;
  const float* A2p = A2 + (size_t)(m0 + am) * K + akb * 8;
  const float* Bp = B + (size_t)(bkb * 8) * N + n0 + bn;
  float ar[AF], ar2[FS ? AF : 1], br[16];
  f32x4v acc[MI][4];
  #pragma unroll
  for (int i = 0; i < MI; ++i)
    #pragma unroll
    for (int j = 0; j < 4; ++j)
      #pragma unroll
      for (int r2 = 0; r2 < 4; ++r2) acc[i][j][r2] = 0.f;
  const int NT = K >> 5;
  #pragma unroll
  for (int q2 = 0; q2 < AF / 4; ++q2)
    *(float4*)&ar[q2 * 4] = *(const float4*)(Ap + q2 * 4);
  if (FS) {
    #pragma unroll
    for (int q2 = 0; q2 < AF / 4; ++q2)
      *(float4*)&ar2[q2 * 4] = *(const float4*)(A2p + q2 * 4);
  }
  #pragma unroll
  for (int j = 0; j < 16; ++j) br[j] = Bp[(size_t)j * N];
  for (int t = 0; t < NT; ++t) {
    __syncthreads();
    float av[AF];
    #pragma unroll
    for (int u = 0; u < AF; ++u) {
      float g = ar[u];
      av[u] = FS ? (g / (1.f + expf(-g))) * ar2[u] : g;
    }
    *(uint4*)&Al[akb][am][0] = make_uint4(
        pack2h(av[0], av[1]), pack2h(av[2], av[3]),
        pack2h(av[4], av[5]), pack2h(av[6], av[7]));
    if (TM == 128) {
      *(uint4*)&Al[akb + 1][am][0] = make_uint4(
          pack2h(av[8], av[9]), pack2h(av[10], av[11]),
          pack2h(av[12], av[13]), pack2h(av[14], av[15]));
    }
    *(uint4*)&Bl[bkb][bn][0] = make_uint4(
        pack2h(br[0], br[1]), pack2h(br[2], br[3]),
        pack2h(br[4], br[5]), pack2h(br[6], br[7]));
    *(uint4*)&Bl[bkb + 1][bn][0] = make_uint4(
        pack2h(br[8], br[9]), pack2h(br[10], br[11]),
        pack2h(br[12], br[13]), pack2h(br[14], br[15]));
    if (t + 1 < NT) {
      Ap += 32; A2p += 32; Bp += (size_t)32 * N;
      #pragma unroll
      for (int q2 = 0; q2 < AF / 4; ++q2)
        *(float4*)&ar[q2 * 4] = *(const float4*)(Ap + q2 * 4);
      if (FS) {
        #pragma unroll
        for (int q2 = 0; q2 < AF / 4; ++q2)
          *(float4*)&ar2[q2 * 4] = *(const float4*)(A2p + q2 * 4);
      }
      #pragma unroll
      for (int j = 0; j < 16; ++j) br[j] = Bp[(size_t)j * N];
    }
    __syncthreads();
    f16x8 af[MI], bfr[4];
    #pragma unroll
    for (int mi = 0; mi < MI; ++mi)
      af[mi] = *(const f16x8*)&Al[lg][wm + mi * 16 + lr][0];
    #pragma unroll
    for (int ni = 0; ni < 4; ++ni)
      bfr[ni] = *(const f16x8*)&Bl[lg][wn + ni * 16 + lr][0];
    #pragma unroll
    for (int mi = 0; mi < MI; ++mi)
      #pragma unroll
      for (int ni = 0; ni < 4; ++ni)
        acc[mi][ni] = __builtin_amdgcn_mfma_f32_16x16x32_f16(
            af[mi], bfr[ni], acc[mi][ni], 0, 0, 0);
  }
  #pragma unroll
  for (int mi = 0; mi < MI; ++mi) {
    #pragma unroll
    for (int ni = 0; ni < 4; ++ni) {
      const int rr = m0 + wm + mi * 16 + lg * 4;
      const int cc = n0 + wn + ni * 16 + lr;
      #pragma unroll
      for (int r2 = 0; r2 < 4; ++r2) {
        float* cp = C + (size_t)(rr + r2) * N + cc;
        if (ACC) *cp += acc[mi][ni][r2];
        else     *cp = acc[mi][ni][r2];
      }
    }
  }
}

// =================================================================
// embedding gather
// =================================================================
__global__ __launch_bounds__(256) void embed_k(const int* __restrict__ ids,
    const float* __restrict__ emb, float* __restrict__ hid) {
  int t = blockIdx.x * 256 + threadIdx.x;
  int s = t >> 9;
  int c4 = (t & 511) * 4;
  *(float4*)(hid + (size_t)s * HIDN + c4) =
      *(const float4*)(emb + (size_t)ids[s] * HIDN + c4);
}

// =================================================================
// rmsnorm over HIDN=2048; also emits fp16 A-image [mp64][kt][kb][m][j]
// =================================================================
__global__ __launch_bounds__(256) void rmsnorm_k(const float* __restrict__ in,
    const float* __restrict__ w, float* __restrict__ out,
    ushort_t* __restrict__ x16) {
  const int row = blockIdx.x;
  const float* ip = in + (size_t)row * HIDN;
  float ss = 0.f;
  for (int c = threadIdx.x * 4; c < HIDN; c += 1024) {
    float4 v = *(const float4*)(ip + c);
    ss += v.x * v.x + v.y * v.y + v.z * v.z + v.w * v.w;
  }
  #pragma unroll
  for (int o = 32; o > 0; o >>= 1) ss += __shfl_down(ss, o, 64);
  __shared__ float sred[4];
  if ((threadIdx.x & 63) == 0) sred[threadIdx.x >> 6] = ss;
  __syncthreads();
  float tot = sred[0] + sred[1] + sred[2] + sred[3];
  float sc = 1.f / sqrtf(tot * (1.f / HIDN) + 1e-6f);
  const int m = row & 63, mp = row >> 6;
  ushort_t* xb = x16 + (size_t)mp * (HIDN >> 5) * 2048 + m * 8;
  for (int c = threadIdx.x * 4; c < HIDN; c += 1024) {
    float4 v = *(const float4*)(ip + c);
    float4 o = make_float4(v.x * sc * w[c], v.y * sc * w[c + 1],
                           v.z * sc * w[c + 2], v.w * sc * w[c + 3]);
    *(float4*)(out + (size_t)row * HIDN + c) = o;
    int kt = c >> 5, kb = (c >> 3) & 3, j = c & 7;
    *(uint2*)(xb + (size_t)kt * 2048 + kb * 512 + j) =
        make_uint2(pack2h(o.x, o.y), pack2h(o.z, o.w));
  }
}

// =================================================================
// new_conv = last 4 time rows of mixed (raw, pre-silu), [c][kk]
// =================================================================
__global__ __launch_bounds__(256) void newconv_k(const float* __restrict__ mixed,
                                                 float* __restrict__ nc) {
  int t = blockIdx.x * 256 + threadIdx.x;
  int c = t >> 2, kk = t & 3;
  nc[t] = mixed[(size_t)(1020 + kk) * CDIM + c];
}

// =================================================================
// causal conv (K=4) + silu
// =================================================================
__global__ __launch_bounds__(256) void conv_k(const float* __restrict__ mixed,
    const float* __restrict__ cstate, const float* __restrict__ cw,
    const float* __restrict__ cb, float* __restrict__ convo) {
  int idx = blockIdx.x * 256 + threadIdx.x;
  int c = idx & (CDIM - 1);
  int s = idx >> 12;
  float acc = cb[c];
  #pragma unroll
  for (int kk = 0; kk < 4; ++kk) {
    int j = s + 1 + kk;
    float pv = (j < 4) ? cstate[c * 4 + j] : mixed[(size_t)(j - 4) * CDIM + c];
    acc = fmaf(cw[c * 4 + kk], pv, acc);
  }
  convo[(size_t)s * CDIM + c] = acc / (1.f + expf(-acc));
}

// =================================================================
// delta q/k L2-normalize; layout out: [h8][s][128]
// =================================================================
__global__ __launch_bounds__(128) void qknorm_k(const float* __restrict__ convo,
    float* __restrict__ qn, float* __restrict__ kn) {
  const int b = blockIdx.x;
  const int h8 = b & 7, s = b >> 3;
  const int d = threadIdx.x;
  float qv = convo[(size_t)s * CDIM + h8 * 128 + d];
  float kv = convo[(size_t)s * CDIM + 1024 + h8 * 128 + d];
  __shared__ float sred[4];
  float pq = qv * qv, pk = kv * kv;
  #pragma unroll
  for (int o = 32; o > 0; o >>= 1) { pq += __shfl_down(pq, o, 64); pk += __shfl_down(pk, o, 64); }
  if ((d & 63) == 0) { sred[d >> 6] = pq; sred[2 + (d >> 6)] = pk; }
  __syncthreads();
  float sq = sred[0] + sred[1], sk = sred[2] + sred[3];
  qn[((size_t)h8 * S_LEN + s) * 128 + d] = qv * (1.f / sqrtf(sq + 1e-6f)) * 0.08838834764831845f;
  kn[((size_t)h8 * S_LEN + s) * 128 + d] = kv * (1.f / sqrtf(sk + 1e-6f));
}

// =================================================================
// beta = sigmoid(x@b_w), g = -exp(A_log)*softplus(x@a_w + dt_bias)
// =================================================================
__global__ __launch_bounds__(256) void betag_k(const float* __restrict__ x,
    const float* __restrict__ bw, const float* __restrict__ aw,
    const float* __restrict__ A_log, const float* __restrict__ dt_bias,
    float* __restrict__ beta, float* __restrict__ g) {
  __shared__ float sx[2048];
  __shared__ float rb[16][17], ra[16][17];
  const int s = blockIdx.x;
  for (int c = threadIdx.x; c < HIDN; c += 256) sx[c] = x[(size_t)s * HIDN + c];
  __syncthreads();
  const int h = threadIdx.x & 15, part = threadIdx.x >> 4;
  float accb = 0.f, acca = 0.f;
  for (int j = 0; j < 128; ++j) {
    int k = part * 128 + j;
    float xv = sx[k];
    accb = fmaf(xv, bw[(size_t)k * 16 + h], accb);
    acca = fmaf(xv, aw[(size_t)k * 16 + h], acca);
  }
  rb[part][h] = accb; ra[part][h] = acca;
  __syncthreads();
  if (threadIdx.x < 16) {
    const int hh = threadIdx.x;
    float sb = 0.f, sa = 0.f;
    for (int p = 0; p < 16; ++p) { sb += rb[p][hh]; sa += ra[p][hh]; }
    beta[(size_t)s * 16 + hh] = 1.f / (1.f + expf(-sb));
    float aa = sa + dt_bias[hh];
    float sp = (aa > 20.f) ? aa : log1pf(expf(aa));
    g[(size_t)s * 16 + hh] = -expf(A_log[hh]) * sp;
  }
}

// =================================================================
// delta phase 1
// =================================================================
__global__ __launch_bounds__(256) void delta_phase1(
    const float* __restrict__ qn, const float* __restrict__ kn,
    const float* __restrict__ convo, const float* __restrict__ beta,
    const float* __restrict__ g,
    float* __restrict__ Wb, ushort_t* __restrict__ KC16,
    ushort_t* __restrict__ Q16, ushort_t* __restrict__ K16,
    ushort_t* __restrict__ ATT16, float* __restrict__ GCb) {
  __shared__ float sK[64][129];
  __shared__ float sV[64][129];
  __shared__ float sQ[64][129];
  __shared__ float sT[64][64];
  __shared__ float sgc[64], sbeta[64], seg[64], sEgl[64];
  const int blk = blockIdx.x;
  const int n = blk & 15, h = blk >> 4;
  const int hq = h >> 1;
  const int r0 = n * 64;
  const int tid = threadIdx.x;
  const size_t hn = (size_t)h * 16 + n;
  for (int t = tid; t < 2048; t += 256) {
    int i = t >> 5, c4 = (t & 31) * 4;
    float4 kv = *(const float4*)(kn + ((size_t)hq * S_LEN + r0 + i) * 128 + c4);
    float4 qv = *(const float4*)(qn + ((size_t)hq * S_LEN + r0 + i) * 128 + c4);
    float4 vv = *(const float4*)(convo + (size_t)(r0 + i) * CDIM + 2048 + h * 128 + c4);
    sK[i][c4+0]=kv.x; sK[i][c4+1]=kv.y; sK[i][c4+2]=kv.z; sK[i][c4+3]=kv.w;
    sQ[i][c4+0]=qv.x; sQ[i][c4+1]=qv.y; sQ[i][c4+2]=qv.z; sQ[i][c4+3]=qv.w;
    sV[i][c4+0]=vv.x; sV[i][c4+1]=vv.y; sV[i][c4+2]=vv.z; sV[i][c4+3]=vv.w;
  }
  if (tid < 64) sbeta[tid] = beta[(size_t)(r0 + tid) * NVH + h];
  __syncthreads();
  if (tid == 0) {
    float acc = 0.f;
    for (int i = 0; i < 64; ++i) { acc += g[(size_t)(r0 + i) * NVH + h]; sgc[i] = acc; }
  }
  __syncthreads();
  if (tid < 64) {
    seg[tid] = expf(sgc[tid]);
    sEgl[tid] = expf(sgc[63] - sgc[tid]);
  }
  {
    const int ty = tid >> 4, tx = tid & 15;
    float a[4][4] = {};
    #pragma unroll 4
    for (int k = 0; k < 128; ++k) {
      float kr[4], kc_[4];
      #pragma unroll
      for (int di = 0; di < 4; ++di) kr[di] = sK[ty * 4 + di][k];
      #pragma unroll
      for (int dj = 0; dj < 4; ++dj) kc_[dj] = sK[tx * 4 + dj][k];
      #pragma unroll
      for (int di = 0; di < 4; ++di)
        #pragma unroll
        for (int dj = 0; dj < 4; ++dj)
          a[di][dj] = fmaf(kr[di], kc_[dj], a[di][dj]);
    }
    #pragma unroll
    for (int di = 0; di < 4; ++di) {
      int i = ty * 4 + di;
      #pragma unroll
      for (int dj = 0; dj < 4; ++dj) {
        int j = tx * 4 + dj;
        float v;
        if (i > j) v = sbeta[i] * a[di][dj] * expf(sgc[i] - sgc[j]);
        else v = (i == j) ? 1.f : 0.f;
        sT[i][j] = v;
      }
    }
  }
  __syncthreads();
  if (tid < 64) {
    const int c = tid;
    for (int i = 1; i < 64; ++i) {
      if (c <= i) {
        float acc = (c == i) ? 1.f : 0.f;
        for (int j = c; j < i; ++j) acc -= sT[i][j] * sT[j][c];
        sT[i][c] = acc;
      }
    }
  }
  __syncthreads();
  for (int t = tid; t < 1024; t += 256) {
    int i = t >> 4, dg = (t & 15) * 8;
    float aw[8] = {}, ak[8] = {};
    for (int j = 0; j <= i; ++j) {
      float tv = sT[i][j] * sbeta[j];
      float te = tv * seg[j];
      #pragma unroll
      for (int u = 0; u < 8; ++u) {
        aw[u] = fmaf(tv, sV[j][dg + u], aw[u]);
        ak[u] = fmaf(te, sK[j][dg + u], ak[u]);
      }
    }
    float* wp = Wb + (hn * 64 + i) * 128 + dg;
    *(float4*)wp = make_float4(aw[0], aw[1], aw[2], aw[3]);
    *(float4*)(wp + 4) = make_float4(aw[4], aw[5], aw[6], aw[7]);
    uint4 kc = make_uint4(pack2h(-ak[0], -ak[1]), pack2h(-ak[2], -ak[3]),
                          pack2h(-ak[4], -ak[5]), pack2h(-ak[6], -ak[7]));
    *(uint4*)(KC16 + hn * 8192 + (dg >> 3) * 512 + i * 8) = kc;
  }
  for (int t = tid; t < 1024; t += 256) {
    int i = t >> 4, dg = (t & 15) * 8;
    float e = seg[i];
    uint4 qv = make_uint4(
        pack2h(sQ[i][dg] * e, sQ[i][dg + 1] * e),
        pack2h(sQ[i][dg + 2] * e, sQ[i][dg + 3] * e),
        pack2h(sQ[i][dg + 4] * e, sQ[i][dg + 5] * e),
        pack2h(sQ[i][dg + 6] * e, sQ[i][dg + 7] * e));
    *(uint4*)(Q16 + hn * 8192 + (dg >> 3) * 512 + i * 8) = qv;
  }
  for (int t = tid; t < 1024; t += 256) {
    int kv = t & 127, ib = t >> 7;
    int i0 = ib * 8;
    uint4 kk2 = make_uint4(
        pack2h(sK[i0 + 0][kv] * sEgl[i0 + 0], sK[i0 + 1][kv] * sEgl[i0 + 1]),
        pack2h(sK[i0 + 2][kv] * sEgl[i0 + 2], sK[i0 + 3][kv] * sEgl[i0 + 3]),
        pack2h(sK[i0 + 4][kv] * sEgl[i0 + 4], sK[i0 + 5][kv] * sEgl[i0 + 5]),
        pack2h(sK[i0 + 6][kv] * sEgl[i0 + 6], sK[i0 + 7][kv] * sEgl[i0 + 7]));
    *(uint4*)(K16 + hn * 8192 + ib * 1024 + kv * 8) = kk2;
  }
  __syncthreads();
  {
    const int ty = tid >> 4, tx = tid & 15;
    float a[4][4] = {};
    #pragma unroll 4
    for (int k = 0; k < 128; ++k) {
      float qr[4], kc_[4];
      #pragma unroll
      for (int di = 0; di < 4; ++di) qr[di] = sQ[ty * 4 + di][k];
      #pragma unroll
      for (int dj = 0; dj < 4; ++dj) kc_[dj] = sK[tx * 4 + dj][k];
      #pragma unroll
      for (int di = 0; di < 4; ++di)
        #pragma unroll
        for (int dj = 0; dj < 4; ++dj)
          a[di][dj] = fmaf(qr[di], kc_[dj], a[di][dj]);
    }
    #pragma unroll
    for (int di = 0; di < 4; ++di) {
      int i = ty * 4 + di;
      #pragma unroll
      for (int dj = 0; dj < 4; ++dj) {
        int j = tx * 4 + dj;
        float v = 0.f;
        if (i >= j) v = a[di][dj] * expf(sgc[i] - sgc[j]);
        sT[i][j] = v;
      }
    }
  }
  __syncthreads();
  for (int t = tid; t < 512; t += 256) {
    int i = t >> 3, jb = t & 7;
    const float* ap = &sT[i][jb * 8];
    uint4 av = make_uint4(pack2h(ap[0], ap[1]), pack2h(ap[2], ap[3]),
                          pack2h(ap[4], ap[5]), pack2h(ap[6], ap[7]));
    *(uint4*)(ATT16 + hn * 4096 + jb * 512 + i * 8) = av;
  }
  if (tid < 64) GCb[hn * 64 + tid] = sgc[tid];
}

// =================================================================
// delta phase 2 (MFMA): state in accumulators across 16 chunks
// =================================================================
__global__ __launch_bounds__(256) void delta_phase2(
    const ushort_t* __restrict__ KC16, const ushort_t* __restrict__ Q16,
    const ushort_t* __restrict__ K16, const ushort_t* __restrict__ ATT16,
    const float* __restrict__ Wb, const float* __restrict__ GCb,
    const float* __restrict__ rec_state,
    float* __restrict__ core, float* __restrict__ new_rec) {
  __shared__ uint4 bufKC[1024];
  __shared__ uint4 bufQ[1024];
  __shared__ uint4 bufK[1024];
  __shared__ uint4 bufA[512];
  __shared__ uint4 bufS[512];
  __shared__ uint4 bufV[256];
  ushort_t* sKC = (ushort_t*)bufKC;
  ushort_t* sQ6 = (ushort_t*)bufQ;
  ushort_t* sK6 = (ushort_t*)bufK;
  ushort_t* sAT = (ushort_t*)bufA;
  ushort_t* sS  = (ushort_t*)bufS;
  ushort_t* sVn = (ushort_t*)bufV;
  const int h = blockIdx.x >> 2, ds = blockIdx.x & 3;
  const int d0 = ds * 32;
  const int tid = threadIdx.x;
  const int w = tid >> 6;
  const int lane = tid & 63, lr = lane & 15, lg = lane >> 4;
  const int rowS0 = w * 32;
  f32x4v aS[2][2];
  #pragma unroll
  for (int tm = 0; tm < 2; ++tm)
    #pragma unroll
    for (int tn = 0; tn < 2; ++tn)
      #pragma unroll
      for (int r = 0; r < 4; ++r) {
        int row = rowS0 + tm * 16 + lg * 4 + r;
        int col = tn * 16 + lr;
        aS[tm][tn][r] = rec_state[((size_t)h * 128 + row) * 128 + d0 + col];
      }
  for (int n = 0; n < 16; ++n) {
    const size_t hn = (size_t)h * 16 + n;
    const uint4* pKC = (const uint4*)(KC16 + hn * 8192);
    const uint4* pQ  = (const uint4*)(Q16  + hn * 8192);
    const uint4* pK  = (const uint4*)(K16  + hn * 8192);
    const uint4* pA  = (const uint4*)(ATT16 + hn * 4096);
    uint4 stKC[4], stQ[4], stK[4], stA[2];
    #pragma unroll
    for (int u = 0; u < 4; ++u) {
      stKC[u] = pKC[tid + u * 256];
      stQ[u]  = pQ[tid + u * 256];
      stK[u]  = pK[tid + u * 256];
    }
    #pragma unroll
    for (int u = 0; u < 2; ++u) stA[u] = pA[tid + u * 256];
    const float egl = expf(GCb[hn * 64 + 63]);
    float wseed[2][4];
    #pragma unroll
    for (int tn = 0; tn < 2; ++tn)
      #pragma unroll
      for (int r = 0; r < 4; ++r)
        wseed[tn][r] = Wb[(hn * 64 + (w * 16 + lg * 4 + r)) * 128 + d0 + tn * 16 + lr];
    #pragma unroll
    for (int tm = 0; tm < 2; ++tm)
      #pragma unroll
      for (int tn = 0; tn < 2; ++tn)
        #pragma unroll
        for (int r = 0; r < 4; ++r) {
          int row = rowS0 + tm * 16 + lg * 4 + r;
          int col = tn * 16 + lr;
          sS[(row >> 3) * 256 + col * 8 + (row & 7)] = h16(aS[tm][tn][r]);
        }
    #pragma unroll
    for (int u = 0; u < 4; ++u) {
      bufKC[tid + u * 256] = stKC[u];
      bufQ[tid + u * 256]  = stQ[u];
      bufK[tid + u * 256]  = stK[u];
    }
    #pragma unroll
    for (int u = 0; u < 2; ++u) bufA[tid + u * 256] = stA[u];
    __syncthreads();
    f32x4v aV[2];
    #pragma unroll
    for (int tn = 0; tn < 2; ++tn)
      #pragma unroll
      for (int r = 0; r < 4; ++r) aV[tn][r] = wseed[tn][r];
    #pragma unroll
    for (int c = 0; c < 4; ++c) {
      f16x8 a = *(const f16x8*)&sKC[((c * 4 + lg) * 64 + w * 16 + lr) * 8];
      #pragma unroll
      for (int tn = 0; tn < 2; ++tn) {
        f16x8 b = *(const f16x8*)&sS[((c * 4 + lg) * 32 + tn * 16 + lr) * 8];
        aV[tn] = __builtin_amdgcn_mfma_f32_16x16x32_f16(a, b, aV[tn], 0, 0, 0);
      }
    }
    #pragma unroll
    for (int tn = 0; tn < 2; ++tn)
      #pragma unroll
      for (int r = 0; r < 4; ++r) {
        int row = w * 16 + lg * 4 + r;
        int col = tn * 16 + lr;
        sVn[(row >> 3) * 256 + col * 8 + (row & 7)] = h16(aV[tn][r]);
      }
    __syncthreads();
    f32x4v aO[2];
    #pragma unroll
    for (int tn = 0; tn < 2; ++tn)
      #pragma unroll
      for (int r = 0; r < 4; ++r) aO[tn][r] = 0.f;
    #pragma unroll
    for (int c = 0; c < 4; ++c) {
      f16x8 a = *(const f16x8*)&sQ6[((c * 4 + lg) * 64 + w * 16 + lr) * 8];
      #pragma unroll
      for (int tn = 0; tn < 2; ++tn) {
        f16x8 b = *(const f16x8*)&sS[((c * 4 + lg) * 32 + tn * 16 + lr) * 8];
        aO[tn] = __builtin_amdgcn_mfma_f32_16x16x32_f16(a, b, aO[tn], 0, 0, 0);
      }
    }
    #pragma unroll
    for (int c = 0; c < 2; ++c) {
      f16x8 a = *(const f16x8*)&sAT[((c * 4 + lg) * 64 + w * 16 + lr) * 8];
      #pragma unroll
      for (int tn = 0; tn < 2; ++tn) {
        f16x8 b = *(const f16x8*)&sVn[((c * 4 + lg) * 32 + tn * 16 + lr) * 8];
        aO[tn] = __builtin_amdgcn_mfma_f32_16x16x32_f16(a, b, aO[tn], 0, 0, 0);
      }
    }
    #pragma unroll
    for (int tn = 0; tn < 2; ++tn)
      #pragma unroll
      for (int r = 0; r < 4; ++r) {
        int row = w * 16 + lg * 4 + r;
        core[(size_t)(n * 64 + row) * HIDN + h * 128 + d0 + tn * 16 + lr] = aO[tn][r];
      }
    #pragma unroll
    for (int tm = 0; tm < 2; ++tm)
      #pragma unroll
      for (int tn = 0; tn < 2; ++tn)
        #pragma unroll
        for (int r = 0; r < 4; ++r) aS[tm][tn][r] *= egl;
    #pragma unroll
    for (int tm = 0; tm < 2; ++tm) {
      #pragma unroll
      for (int c = 0; c < 2; ++c) {
        f16x8 a = *(const f16x8*)&sK6[((c * 4 + lg) * 128 + rowS0 + tm * 16 + lr) * 8];
        #pragma unroll
        for (int tn = 0; tn < 2; ++tn) {
          f16x8 b = *(const f16x8*)&sVn[((c * 4 + lg) * 32 + tn * 16 + lr) * 8];
          aS[tm][tn] = __builtin_amdgcn_mfma_f32_16x16x32_f16(a, b, aS[tm][tn], 0, 0, 0);
        }
      }
    }
    __syncthreads();
  }
  #pragma unroll
  for (int tm = 0; tm < 2; ++tm)
    #pragma unroll
    for (int tn = 0; tn < 2; ++tn)
      #pragma unroll
      for (int r = 0; r < 4; ++r) {
        int row = rowS0 + tm * 16 + lg * 4 + r;
        int col = tn * 16 + lr;
        new_rec[((size_t)h * 128 + row) * 128 + d0 + col] = aS[tm][tn][r];
      }
}

// =================================================================
// gated rmsnorm over DV=128 rows -> fp16 A-image only
// =================================================================
__global__ __launch_bounds__(128) void gatedrms_k(const float* __restrict__ core,
    const float* __restrict__ z, const float* __restrict__ w,
    ushort_t* __restrict__ c16) {
  const int b = blockIdx.x;
  const int h = b & 15, s = b >> 4;
  const int d = threadIdx.x;
  size_t idx = (size_t)s * HIDN + h * 128 + d;
  float cv = core[idx], zv = z[idx];
  float xf = cv * (zv / (1.f + expf(-zv)));
  __shared__ float sred[2];
  float ps = xf * xf;
  #pragma unroll
  for (int o = 32; o > 0; o >>= 1) ps += __shfl_down(ps, o, 64);
  if ((d & 63) == 0) sred[d >> 6] = ps;
  __syncthreads();
  float ss = sred[0] + sred[1];
  float val = xf * (1.f / sqrtf(ss * (1.f / 128.f) + 1e-6f)) * w[d];
  float nb = __shfl_down(val, 1, 64);
  if (!(d & 1)) {
    int c = h * 128 + d;
    int kt = c >> 5, kb = (c >> 3) & 3, j = c & 7;
    int m = s & 63, mp = s >> 6;
    *(unsigned int*)(c16 + (size_t)mp * 131072 + kt * 2048 + kb * 512 + m * 8 + j)
        = pack2h(val, nb);
  }
}

// =================================================================
// attention q: rmsnorm(q_norm_w) + rope; also extract gate
// =================================================================
__global__ __launch_bounds__(128) void qrope_k(const float* __restrict__ qg,
    const float* __restrict__ qnw, const float* __restrict__ cosb,
    const float* __restrict__ sinb, float* __restrict__ qhat,
    float* __restrict__ agate) {
  const int b = blockIdx.x;
  const int h = b & 15, s = b >> 4;
  const int d = threadIdx.x;
  float qv = qg[(size_t)s * 4096 + h * 256 + d];
  float gv = qg[(size_t)s * 4096 + h * 256 + 128 + d];
  __shared__ float sred[2];
  float ps = qv * qv;
  #pragma unroll
  for (int o = 32; o > 0; o >>= 1) ps += __shfl_down(ps, o, 64);
  if ((d & 63) == 0) sred[d >> 6] = ps;
  __syncthreads();
  float ss = sred[0] + sred[1];
  float qn_ = qv * (1.f / sqrtf(ss * (1.f / 128.f) + 1e-6f)) * qnw[d];
  __shared__ float tmp[128];
  tmp[d] = qn_;
  __syncthreads();
  float other = tmp[d ^ 64];
  float rh = (d < 64) ? -other : other;
  float c = cosb[(size_t)s * 128 + d];
  float sn = sinb[(size_t)s * 128 + d];
  qhat[((size_t)h * S_LEN + s) * 128 + d] = qn_ * c + rh * sn;
  agate[(size_t)s * HIDN + h * 128 + d] = gv;
}

// =================================================================
// attention k: rmsnorm + rope -> kcache rows SP..; v -> vcache
// =================================================================
__global__ __launch_bounds__(128) void kvrope_k(const float* __restrict__ kraw,
    const float* __restrict__ vraw, const float* __restrict__ knw,
    const float* __restrict__ cosb, const float* __restrict__ sinb,
    float* __restrict__ kcache, float* __restrict__ vcache) {
  const int b = blockIdx.x;
  const int h2 = b & 1, s = b >> 1;
  const int d = threadIdx.x;
  float kv = kraw[(size_t)s * 256 + h2 * 128 + d];
  __shared__ float sred[2];
  float ps = kv * kv;
  #pragma unroll
  for (int o = 32; o > 0; o >>= 1) ps += __shfl_down(ps, o, 64);
  if ((d & 63) == 0) sred[d >> 6] = ps;
  __syncthreads();
  float ss = sred[0] + sred[1];
  float kn_ = kv * (1.f / sqrtf(ss * (1.f / 128.f) + 1e-6f)) * knw[d];
  __shared__ float tmp[128];
  tmp[d] = kn_;
  __syncthreads();
  float other = tmp[d ^ 64];
  float rh = (d < 64) ? -other : other;
  size_t row = (size_t)h2 * MAXKV + SP + s;
  kcache[row * 128 + d] = kn_ * cosb[(size_t)s * 128 + d] + rh * sinb[(size_t)s * 128 + d];
  vcache[row * 128 + d] = vraw[(size_t)s * 256 + h2 * 128 + d];
}

// =================================================================
// KV cache -> fp16 pre-swizzled tiles for attn (rows 0..1535)
// =================================================================
__global__ __launch_bounds__(256) void kv16_k(const float* __restrict__ kc,
    const float* __restrict__ vc, ushort_t* __restrict__ KV16) {
  const int b = blockIdx.x;            // 48 blocks
  const int kt = b % 24, h2 = b / 24;
  const int tid = threadIdx.x;
  const float* Kb = kc + ((size_t)h2 * MAXKV + kt * 64) * 128;
  const float* Vb = vc + ((size_t)h2 * MAXKV + kt * 64) * 128;
  ushort_t* Ko = KV16 + ((size_t)h2 * 24 + kt) * 8192;
  ushort_t* Vo = KV16 + 393216 + ((size_t)h2 * 24 + kt) * 8192;
  #pragma unroll
  for (int it = 0; it < 4; ++it) {
    int tt = tid + it * 256;
    int row = tt >> 4, kb = tt & 15;
    float4 a = *(const float4*)(Kb + row * 128 + kb * 8);
    float4 c = *(const float4*)(Kb + row * 128 + kb * 8 + 4);
    *(uint4*)(Ko + ((size_t)kb * 64 + row) * 8) = make_uint4(
        pack2h(a.x, a.y), pack2h(a.z, a.w), pack2h(c.x, c.y), pack2h(c.z, c.w));
  }
  #pragma unroll
  for (int it = 0; it < 4; ++it) {
    int tt = tid + it * 256;
    int key = tt >> 4, dg = tt & 15;
    float4 a = *(const float4*)(Vb + key * 128 + dg * 8);
    float4 c = *(const float4*)(Vb + key * 128 + dg * 8 + 4);
    int base = (key >> 3) * 1024 + (key & 7);
    Vo[base + (dg * 8 + 0) * 8] = h16(a.x);
    Vo[base + (dg * 8 + 1) * 8] = h16(a.y);
    Vo[base + (dg * 8 + 2) * 8] = h16(a.z);
    Vo[base + (dg * 8 + 3) * 8] = h16(a.w);
    Vo[base + (dg * 8 + 4) * 8] = h16(c.x);
    Vo[base + (dg * 8 + 5) * 8] = h16(c.y);
    Vo[base + (dg * 8 + 6) * 8] = h16(c.z);
    Vo[base + (dg * 8 + 7) * 8] = h16(c.w);
  }
}

// =================================================================
// fp16 MFMA flash attention; K/V via global_load_lds; fp16 A-image out
// =================================================================
__global__ __launch_bounds__(256) void attn_k(const float* __restrict__ qhat,
    const ushort_t* __restrict__ KV16,
    const float* __restrict__ agate, ushort_t* __restrict__ AO16) {
  __shared__ unsigned int Ql[16][64][4];
  __shared__ unsigned int Kl[16][64][4];
  __shared__ unsigned int Vl[8][128][4];
  __shared__ unsigned int Pl[8][64][4];
  const int h = blockIdx.x >> 4, qb = blockIdx.x & 15;
  const int hkv = h >> 3;
  const int tid = threadIdx.x;
  const int wave = tid >> 6, lane = tid & 63;
  const int lr = lane & 15, lg = lane >> 4;
  const float SCALE = 0.08838834764831845f;
  const float* Qb = qhat + ((size_t)h * S_LEN + qb * 64) * 128;
  #pragma unroll
  for (int it = 0; it < 4; ++it) {
    int tt = tid + it * 256;
    int row = tt >> 4, kb = tt & 15;
    float4 a = *(const float4*)(Qb + row * 128 + kb * 8);
    float4 b = *(const float4*)(Qb + row * 128 + kb * 8 + 4);
    *(uint4*)&Ql[kb][row][0] = make_uint4(
        pack2h(a.x * SCALE, a.y * SCALE), pack2h(a.z * SCALE, a.w * SCALE),
        pack2h(b.x * SCALE, b.y * SCALE), pack2h(b.z * SCALE, b.w * SCALE));
  }
  float m_run[4], l_run[4];
  #pragma unroll
  for (int r = 0; r < 4; ++r) { m_run[r] = -3.0e38f; l_run[r] = 0.f; }
  f32x4v accO[8];
  #pragma unroll
  for (int nd = 0; nd < 8; ++nd)
    #pragma unroll
    for (int r = 0; r < 4; ++r) accO[nd][r] = 0.f;
  const int ntiles = 9 + qb;
  for (int kt = 0; kt < ntiles; ++kt) {
    __syncthreads();
    const ushort_t* Ks = KV16 + ((size_t)hkv * 24 + kt) * 8192;
    const ushort_t* Vs = KV16 + 393216 + ((size_t)hkv * 24 + kt) * 8192;
    #pragma unroll
    for (int i2 = 0; i2 < 4; ++i2) {
      int c = wave * 4 + i2;
      gload16(Ks + (size_t)c * 512 + lane * 8, (char*)Kl + c * 1024);
      gload16(Vs + (size_t)c * 512 + lane * 8, (char*)Vl + c * 1024);
    }
    __syncthreads();
    f32x4v accS[4];
    #pragma unroll
    for (int ni = 0; ni < 4; ++ni)
      #pragma unroll
      for (int r = 0; r < 4; ++r) accS[ni][r] = 0.f;
    #pragma unroll
    for (int c = 0; c < 4; ++c) {
      f16x8 aq = *(const f16x8*)&Ql[c * 4 + lg][wave * 16 + lr][0];
      #pragma unroll
      for (int ni = 0; ni < 4; ++ni) {
        f16x8 bk = *(const f16x8*)&Kl[c * 4 + lg][ni * 16 + lr][0];
        accS[ni] = __builtin_amdgcn_mfma_f32_16x16x32_f16(aq, bk, accS[ni], 0, 0, 0);
      }
    }
    const bool boundary = (kt == ntiles - 1);
    float alpha[4];
    #pragma unroll
    for (int r = 0; r < 4; ++r) {
      const int qrow = wave * 16 + lg * 4 + r;
      float tm = -3.0e38f;
      #pragma unroll
      for (int ni = 0; ni < 4; ++ni) {
        if (boundary && (ni * 16 + lr) > qrow) accS[ni][r] = -3.0e38f;
        tm = fmaxf(tm, accS[ni][r]);
      }
      tm = fmaxf(tm, __shfl_xor(tm, 1, 64));
      tm = fmaxf(tm, __shfl_xor(tm, 2, 64));
      tm = fmaxf(tm, __shfl_xor(tm, 4, 64));
      tm = fmaxf(tm, __shfl_xor(tm, 8, 64));
      float mnew = fmaxf(m_run[r], tm);
      alpha[r] = expf(m_run[r] - mnew);
      m_run[r] = mnew;
      float ls = 0.f;
      #pragma unroll
      for (int ni = 0; ni < 4; ++ni) {
        float p = expf(accS[ni][r] - mnew);
        accS[ni][r] = p;
        ls += p;
      }
      ls += __shfl_xor(ls, 1, 64);
      ls += __shfl_xor(ls, 2, 64);
      ls += __shfl_xor(ls, 4, 64);
      ls += __shfl_xor(ls, 8, 64);
      l_run[r] = l_run[r] * alpha[r] + ls;
    }
    {
      _Float16* pp = (_Float16*)Pl;
      #pragma unroll
      for (int ni = 0; ni < 4; ++ni) {
        int key = ni * 16 + lr;
        int base = (key >> 3) * 512 + (key & 7);
        #pragma unroll
        for (int r = 0; r < 4; ++r) {
          int q = wave * 16 + lg * 4 + r;
          pp[base + q * 8] = (_Float16)accS[ni][r];
        }
      }
    }
    #pragma unroll
    for (int nd = 0; nd < 8; ++nd)
      #pragma unroll
      for (int r = 0; r < 4; ++r) accO[nd][r] *= alpha[r];
    #pragma unroll
    for (int c2 = 0; c2 < 2; ++c2) {
      f16x8 ap = *(const f16x8*)&Pl[c2 * 4 + lg][wave * 16 + lr][0];
      #pragma unroll
      for (int nd = 0; nd < 8; ++nd) {
        f16x8 bv = *(const f16x8*)&Vl[c2 * 4 + lg][nd * 16 + lr][0];
        accO[nd] = __builtin_amdgcn_mfma_f32_16x16x32_f16(ap, bv, accO[nd], 0, 0, 0);
      }
    }
  }
  #pragma unroll
  for (int r = 0; r < 4; ++r) {
    const int row = qb * 64 + wave * 16 + lg * 4 + r;
    const int m = row & 63, mp = row >> 6;
    const float inv = 1.f / l_run[r];
    #pragma unroll
    for (int nd = 0; nd < 8; ++nd) {
      int d = nd * 16 + lr;
      float gv = agate[(size_t)row * HIDN + h * 128 + d];
      float val = accO[nd][r] * inv * (1.f / (1.f + expf(-gv)));
      float nb = __shfl_down(val, 1, 64);
      if (!(lr & 1)) {
        int c = h * 128 + d;
        int kt2 = c >> 5, kb2 = (c >> 3) & 3, j2 = c & 7;
        *(unsigned int*)(AO16 + (size_t)mp * 131072 + kt2 * 2048 + kb2 * 512 + m * 8 + j2)
            = pack2h(val, nb);
      }
    }
  }
}

// =================================================================
// host
// =================================================================
static inline void gemmh128(const ushort_t* A16, const float* B, float* C,
                            int M, int N, int K, hipStream_t st) {
  dim3 g((N / 128) * (M / 128));
  hipLaunchKernelGGL((gemm_h<128, false>), g, dim3(256), 0, st, A16, B, C, M, N, K);
}
static inline void gemmh64(const ushort_t* A16, const float* B, float* C,
                           int M, int N, int K, hipStream_t st) {
  dim3 g((N / 128) * (M / 64));
  hipLaunchKernelGGL((gemm_h<64, false>), g, dim3(256), 0, st, A16, B, C, M, N, K);
}
static inline void gemmh64a(const ushort_t* A16, const float* B, float* C,
                            int M, int N, int K, hipStream_t st) {
  dim3 g((N / 128) * (M / 64));
  hipLaunchKernelGGL((gemm_h<64, true>), g, dim3(256), 0, st, A16, B, C, M, N, K);
}
static inline void gemm128(const float* A, const float* B, float* C,
                           int M, int N, int K, bool acc, hipStream_t st) {
  dim3 g((N / 128) * (M / 128));
  if (acc) hipLaunchKernelGGL((gemm_f16<128, true,  false>), g, dim3(256), 0, st, A, A, B, C, M, N, K);
  else     hipLaunchKernelGGL((gemm_f16<128, false, false>), g, dim3(256), 0, st, A, A, B, C, M, N, K);
}
static inline void gemm_dn(const float* G, const float* U, const float* B, float* C,
                           int M, int N, int K, hipStream_t st) {
  dim3 g((N / 128) * (M / 64));
  hipLaunchKernelGGL((gemm_f16<64, true, true>), g, dim3(256), 0, st, G, U, B, C, M, N, K);
}

extern "C" void kernel_launch(void* const* d_in, const int* in_sizes, int n_in,
                              void* d_out, int out_size, void* d_ws, size_t ws_size,
                              hipStream_t stream) {
  (void)in_sizes; (void)n_in; (void)out_size;
  const int*   ids         = (const int*)  d_in[0];
  const float* rope_cos    = (const float*)d_in[3];
  const float* rope_sin    = (const float*)d_in[4];
  const float* conv_state  = (const float*)d_in[6];
  const float* rec_state   = (const float*)d_in[7];
  const float* key_cache   = (const float*)d_in[8];
  const float* value_cache = (const float*)d_in[9];
  const float* embed_w     = (const float*)d_in[10];
  const float* dl_ln_w     = (const float*)d_in[11];
  const float* dl_qkv_w    = (const float*)d_in[12];
  const float* conv_w      = (const float*)d_in[13];
  const float* conv_b      = (const float*)d_in[14];
  const float* dl_z_w      = (const float*)d_in[15];
  const float* dl_b_w      = (const float*)d_in[16];
  const float* dl_a_w      = (const float*)d_in[17];
  const float* A_log       = (const float*)d_in[18];
  const float* dt_bias     = (const float*)d_in[19];
  const float* dn_norm_w   = (const float*)d_in[20];
  const float* dl_out_w    = (const float*)d_in[21];
  const float* dl_post_ln  = (const float*)d_in[22];
  const float* dl_gate_w   = (const float*)d_in[23];
  const float* dl_up_w     = (const float*)d_in[24];
  const float* dl_down_w   = (const float*)d_in[25];
  const float* al_ln_w     = (const float*)d_in[26];
  const float* q_w         = (const float*)d_in[27];
  const float* q_norm_w    = (const float*)d_in[28];
  const float* k_w         = (const float*)d_in[29];
  const float* k_norm_w    = (const float*)d_in[30];
  const float* v_w         = (const float*)d_in[31];
  const float* o_w         = (const float*)d_in[32];
  const float* al_post_ln  = (const float*)d_in[33];
  const float* al_gate_w   = (const float*)d_in[34];
  const float* al_up_w     = (const float*)d_in[35];
  const float* al_down_w   = (const float*)d_in[36];
  const float* final_norm  = (const float*)d_in[37];
  const float* lm_head_w   = (const float*)d_in[38];

  float* out = (float*)d_out;
  float* logits   = out;                 // 1024*32000 = 32,768,000
  float* new_conv = out + 32768000;      // 16,384
  float* new_rec  = out + 32784384;      // 262,144
  float* new_kc   = out + 33046528;      // 1,048,576
  float* new_vc   = out + 34095104;      // 1,048,576

  // scratch arena inside the logits region (fully dead before final GEMM)
  float* A_mixed = logits;               // 4,194,304
  float* A_convo = logits + 4194304;     // 4,194,304
  float* A_z     = logits + 8388608;     // 2,097,152
  float* A_qn    = logits + 10485760;    // 1,048,576
  float* A_kn    = logits + 11534336;    // 1,048,576 (CORE16 after delta)
  float* A_w     = logits + 12582912;    // 2,097,152 (Wb f32)
  float* A_kc    = logits + 14680064;    // 2,097,152 (8MB -> KC16 + K16)
  float* A_att   = logits + 16777216;    // 1,048,576 (4MB -> Q16)
  float* A_gc    = logits + 17825792;    // 16,384
  float* A_core  = logits + 17842176;    // 2,097,152
  float* A_big0  = logits + 19939328;    // 6,291,456 (ATT16 delta; KV16 attn)
  float* A_big1  = logits + 26230784;    // 6,291,456
  float* A_qhat  = A_big1;               // 2,097,152
  float* A_gate  = A_big1 + 2097152;     // 2,097,152
  float* A_kraw  = A_mixed;              // 262,144 (mixed dead by then)
  float* A_vraw  = A_mixed + 262144;     // 262,144

  ushort_t* KC16  = (ushort_t*)A_kc;             // 4MB
  ushort_t* K16   = (ushort_t*)A_kc + 2097152;   // 4MB
  ushort_t* Q16   = (ushort_t*)A_att;            // 4MB
  ushort_t* ATT16 = (ushort_t*)A_big0;           // 2MB (delta section only)
  ushort_t* KV16  = (ushort_t*)(A_big0 + 4194304); // 1.5MB (attn section only)
  ushort_t* CORE16 = (ushort_t*)A_kn;            // 4MB (post-delta; kn dead)
  ushort_t* AO16   = (ushort_t*)(A_mixed + 524288); // 4MB (post-kvrope)

  float* ws     = (float*)d_ws;
  float* W_hid  = ws;                    // 2,097,152
  float* W_x    = ws + 2097152;          // 2,097,152
  float* W_beta = ws + 4194304;          // 16,384
  float* W_g    = ws + 4210688;          // 16,384

  const bool ws_ok = (ws_size >= (size_t)21102592 + 65536);
  ushort_t* X16 = ws_ok ? (ushort_t*)(ws + 4227072)
                        : (ushort_t*)A_qn;

  // ---- embedding + delta layer ----
  hipLaunchKernelGGL(embed_k, dim3(2048), dim3(256), 0, stream, ids, embed_w, W_hid);
  hipLaunchKernelGGL(rmsnorm_k, dim3(1024), dim3(256), 0, stream, W_hid, dl_ln_w, W_x, X16);
  gemmh128(X16, dl_qkv_w, A_mixed, 1024, 4096, 2048, stream);
  hipLaunchKernelGGL(newconv_k, dim3(64), dim3(256), 0, stream, A_mixed, new_conv);
  hipLaunchKernelGGL(conv_k, dim3(16384), dim3(256), 0, stream,
                     A_mixed, conv_state, conv_w, conv_b, A_convo);
  gemmh64(X16, dl_z_w, A_z, 1024, 2048, 2048, stream);
  hipLaunchKernelGGL(betag_k, dim3(1024), dim3(256), 0, stream,
                     W_x, dl_b_w, dl_a_w, A_log, dt_bias, W_beta, W_g);
  hipLaunchKernelGGL(qknorm_k, dim3(8192), dim3(128), 0, stream, A_convo, A_qn, A_kn);
  hipLaunchKernelGGL(delta_phase1, dim3(256), dim3(256), 0, stream,
                     A_qn, A_kn, A_convo, W_beta, W_g,
                     A_w, KC16, Q16, K16, ATT16, A_gc);
  hipLaunchKernelGGL(delta_phase2, dim3(64), dim3(256), 0, stream,
                     KC16, Q16, K16, ATT16, A_w, A_gc, rec_state, A_core, new_rec);
  hipLaunchKernelGGL(gatedrms_k, dim3(16384), dim3(128), 0, stream,
                     A_core, A_z, dn_norm_w, CORE16);
  gemmh64a(CORE16, dl_out_w, W_hid, 1024, 2048, 2048, stream);
  // ---- MLP 1 ----
  hipLaunchKernelGGL(rmsnorm_k, dim3(1024), dim3(256), 0, stream, W_hid, dl_post_ln, W_x, X16);
  gemmh64(X16, dl_gate_w, A_big0, 1024, 6144, 2048, stream);
  gemmh64(X16, dl_up_w,   A_big1, 1024, 6144, 2048, stream);
  gemm_dn(A_big0, A_big1, dl_down_w, W_hid, 1024, 2048, 6144, stream);
  // ---- softmax attention layer ----
  hipLaunchKernelGGL(rmsnorm_k, dim3(1024), dim3(256), 0, stream, W_hid, al_ln_w, W_x, X16);
  gemmh128(X16, q_w, A_big0, 1024, 4096, 2048, stream);
  hipLaunchKernelGGL(qrope_k, dim3(16384), dim3(128), 0, stream,
                     A_big0, q_norm_w, rope_cos, rope_sin, A_qhat, A_gate);
  gemmh64(X16, k_w, A_kraw, 1024, 256, 2048, stream);
  gemmh64(X16, v_w, A_vraw, 1024, 256, 2048, stream);
  hipMemcpyAsync(new_kc, key_cache,   (size_t)2 * MAXKV * 128 * 4, hipMemcpyDeviceToDevice, stream);
  hipMemcpyAsync(new_vc, value_cache, (size_t)2 * MAXKV * 128 * 4, hipMemcpyDeviceToDevice, stream);
  hipLaunchKernelGGL(kvrope_k, dim3(2048), dim3(128), 0, stream,
                     A_kraw, A_vraw, k_norm_w, rope_cos, rope_sin, new_kc, new_vc);
  hipLaunchKernelGGL(kv16_k, dim3(48), dim3(256), 0, stream, new_kc, new_vc, KV16);
  hipLaunchKernelGGL(attn_k, dim3(256), dim3(256), 0, stream,
                     A_qhat, KV16, A_gate, AO16);
  gemmh64a(AO16, o_w, W_hid, 1024, 2048, 2048, stream);
  // ---- MLP 2 ----
  hipLaunchKernelGGL(rmsnorm_k, dim3(1024), dim3(256), 0, stream, W_hid, al_post_ln, W_x, X16);
  gemmh64(X16, al_gate_w, A_big0, 1024, 6144, 2048, stream);
  gemmh64(X16, al_up_w,   A_big1, 1024, 6144, 2048, stream);
  gemm_dn(A_big0, A_big1, al_down_w, W_hid, 1024, 2048, 6144, stream);
  // ---- final norm + lm_head (both operands fp16 via global_load_lds) ----
  hipLaunchKernelGGL(rmsnorm_k, dim3(1024), dim3(256), 0, stream, W_hid, final_norm, W_x, X16);
  if (ws_ok) {
    hipLaunchKernelGGL(convw_lm, dim3(32000), dim3(256), 0, stream, lm_head_w);
    ushort_t* lm16 = nullptr;
    hipGetSymbolAddress((void**)&lm16, HIP_SYMBOL(g_LM16));
    dim3 g((LMN / 128) * (1024 / 128));
    hipLaunchKernelGGL(gemm_hh, g, dim3(256), 0, stream, X16, lm16, logits, 1024, LMN, 2048);
  } else {
    gemm128(W_x, lm_head_w, logits, 1024, LMN, 2048, false, stream);
  }
}

// Round 15
// 1566.179 us; speedup vs baseline: 1.0943x; 1.0943x over previous
//
#include <hip/hip_runtime.h>
#include <math.h>

// ---------------- model constants ----------------
#define S_LEN 1024
#define HIDN  2048
#define NVH   16      // NV heads (delta v)
#define CDIM  4096    // conv dim
#define MAXKV 4096
#define SP    512
#define LMN   32000
// attention: NQ=16 heads, NKV=2, HD=128

typedef __attribute__((ext_vector_type(4))) float f32x4v;
typedef _Float16 f16x8 __attribute__((ext_vector_type(8)));
typedef unsigned short ushort_t;

// f32 pair -> packed fp16 (RTZ, single v_cvt_pkrtz_f16_f32)
__device__ __forceinline__ unsigned int pack2h(float a, float b) {
  auto h = __builtin_amdgcn_cvt_pkrtz(a, b);   // __fp16 ext_vector(2)
  return __builtin_bit_cast(unsigned int, h);
}
__device__ __forceinline__ ushort_t h16(float x) {
  auto v = __builtin_amdgcn_cvt_pkrtz(x, x);
  return (ushort_t)__builtin_bit_cast(unsigned int, v);
}
// async global->LDS, 16B per lane; LDS dest = wave-uniform base + lane*16
__device__ __forceinline__ void gload16(const void* g, void* l) {
  __builtin_amdgcn_global_load_lds(
      (const __attribute__((address_space(1))) void*)(g),
      (__attribute__((address_space(3))) void*)(l), 16, 0, 0);
}

// =================================================================
// gemm_h: A = fp16 pre-swizzled image [mp64][kt][kb(4)][m(64)][j(8)]
// staged via global_load_lds; B = f32 [K][N] converted on the fly.
// C[M,N] (+)= A@B.  TM=128/64, BK=32, 4 waves. XCD-chunked 1D grid.
// =================================================================
template<int TM, bool ACC>
__global__ __launch_bounds__(256) void gemm_h(const ushort_t* __restrict__ A16,
    const float* __restrict__ B, float* __restrict__ C, int M, int N, int K) {
  constexpr int MI = TM / 32;
  __shared__ ushort_t Al[TM * 32];
  __shared__ unsigned int Bl[4][128][4];
  const int tid = threadIdx.x;
  const int gm = M / TM;
  const int nwg = gridDim.x;
  const int q = nwg >> 3, r = nwg & 7;
  const int xcd = blockIdx.x & 7, ii = blockIdx.x >> 3;
  const int lin = (xcd < r) ? (xcd * (q + 1) + ii)
                            : (r * (q + 1) + (xcd - r) * q + ii);
  const int m0 = (lin % gm) * TM;
  const int n0 = (lin / gm) * 128;
  const int wave = tid >> 6, lane = tid & 63;
  const int wm = (wave >> 1) * (TM / 2), wn = (wave & 1) * 64;
  const int lr = lane & 15, lg = lane >> 4;
  const int bn = tid & 127, bkb = (tid >> 7) * 2;
  const size_t panstride = (size_t)(K >> 5) * 2048;
  const ushort_t* Apan = A16 + (size_t)(m0 >> 6) * panstride;
  const float* Bp = B + (size_t)(bkb * 8) * N + n0 + bn;
  float br[16];
  f32x4v acc[MI][4];
  #pragma unroll
  for (int i = 0; i < MI; ++i)
    #pragma unroll
    for (int j = 0; j < 4; ++j)
      #pragma unroll
      for (int r2 = 0; r2 < 4; ++r2) acc[i][j][r2] = 0.f;
  const int NT = K >> 5;
  #pragma unroll
  for (int j = 0; j < 16; ++j) br[j] = Bp[(size_t)j * N];
  for (int t = 0; t < NT; ++t) {
    __syncthreads();
    if (TM == 128) {
      #pragma unroll
      for (int i2 = 0; i2 < 2; ++i2) {
        int c = wave * 2 + i2;
        int kb = c >> 1, half = c & 1;
        gload16(Apan + half * panstride + (size_t)t * 2048 + kb * 512 + lane * 8,
                Al + kb * 1024 + half * 512);
      }
    } else {
      int kb = wave;
      gload16(Apan + (size_t)t * 2048 + kb * 512 + lane * 8, Al + kb * 512);
    }
    *(uint4*)&Bl[bkb][bn][0] = make_uint4(
        pack2h(br[0], br[1]), pack2h(br[2], br[3]),
        pack2h(br[4], br[5]), pack2h(br[6], br[7]));
    *(uint4*)&Bl[bkb + 1][bn][0] = make_uint4(
        pack2h(br[8], br[9]), pack2h(br[10], br[11]),
        pack2h(br[12], br[13]), pack2h(br[14], br[15]));
    if (t + 1 < NT) {
      Bp += (size_t)32 * N;
      #pragma unroll
      for (int j = 0; j < 16; ++j) br[j] = Bp[(size_t)j * N];
    }
    __syncthreads();
    f16x8 af[MI], bfr[4];
    #pragma unroll
    for (int mi = 0; mi < MI; ++mi)
      af[mi] = *(const f16x8*)&Al[lg * (TM * 8) + (wm + mi * 16 + lr) * 8];
    #pragma unroll
    for (int ni = 0; ni < 4; ++ni)
      bfr[ni] = *(const f16x8*)&Bl[lg][wn + ni * 16 + lr][0];
    #pragma unroll
    for (int mi = 0; mi < MI; ++mi)
      #pragma unroll
      for (int ni = 0; ni < 4; ++ni)
        acc[mi][ni] = __builtin_amdgcn_mfma_f32_16x16x32_f16(
            af[mi], bfr[ni], acc[mi][ni], 0, 0, 0);
  }
  #pragma unroll
  for (int mi = 0; mi < MI; ++mi) {
    #pragma unroll
    for (int ni = 0; ni < 4; ++ni) {
      const int rr = m0 + wm + mi * 16 + lg * 4;
      const int cc = n0 + wn + ni * 16 + lr;
      #pragma unroll
      for (int r2 = 0; r2 < 4; ++r2) {
        float* cp = C + (size_t)(rr + r2) * N + cc;
        if (ACC) *cp += acc[mi][ni][r2];
        else     *cp = acc[mi][ni][r2];
      }
    }
  }
}

// =================================================================
// gemm_hu: like gemm_h<64,false>, but epilogue computes
// silu(gate[row][col]) * acc and writes fp16 pre-swizzled A-image
// (K-dim of image = N). For the MLP up-projection.
// =================================================================
__global__ __launch_bounds__(256) void gemm_hu(const ushort_t* __restrict__ A16,
    const float* __restrict__ B, const float* __restrict__ gate,
    ushort_t* __restrict__ out16, int M, int N, int K) {
  __shared__ ushort_t Al[64 * 32];
  __shared__ unsigned int Bl[4][128][4];
  const int tid = threadIdx.x;
  const int gm = M >> 6;
  const int nwg = gridDim.x;
  const int q = nwg >> 3, r = nwg & 7;
  const int xcd = blockIdx.x & 7, ii = blockIdx.x >> 3;
  const int lin = (xcd < r) ? (xcd * (q + 1) + ii)
                            : (r * (q + 1) + (xcd - r) * q + ii);
  const int m0 = (lin % gm) * 64;
  const int n0 = (lin / gm) * 128;
  const int wave = tid >> 6, lane = tid & 63;
  const int wm = (wave >> 1) * 32, wn = (wave & 1) * 64;
  const int lr = lane & 15, lg = lane >> 4;
  const int bn = tid & 127, bkb = (tid >> 7) * 2;
  const size_t panstride = (size_t)(K >> 5) * 2048;
  const ushort_t* Apan = A16 + (size_t)(m0 >> 6) * panstride;
  const float* Bp = B + (size_t)(bkb * 8) * N + n0 + bn;
  float br[16];
  f32x4v acc[2][4];
  #pragma unroll
  for (int i = 0; i < 2; ++i)
    #pragma unroll
    for (int j = 0; j < 4; ++j)
      #pragma unroll
      for (int r2 = 0; r2 < 4; ++r2) acc[i][j][r2] = 0.f;
  const int NT = K >> 5;
  #pragma unroll
  for (int j = 0; j < 16; ++j) br[j] = Bp[(size_t)j * N];
  for (int t = 0; t < NT; ++t) {
    __syncthreads();
    int kb = wave;
    gload16(Apan + (size_t)t * 2048 + kb * 512 + lane * 8, Al + kb * 512);
    *(uint4*)&Bl[bkb][bn][0] = make_uint4(
        pack2h(br[0], br[1]), pack2h(br[2], br[3]),
        pack2h(br[4], br[5]), pack2h(br[6], br[7]));
    *(uint4*)&Bl[bkb + 1][bn][0] = make_uint4(
        pack2h(br[8], br[9]), pack2h(br[10], br[11]),
        pack2h(br[12], br[13]), pack2h(br[14], br[15]));
    if (t + 1 < NT) {
      Bp += (size_t)32 * N;
      #pragma unroll
      for (int j = 0; j < 16; ++j) br[j] = Bp[(size_t)j * N];
    }
    __syncthreads();
    f16x8 af[2], bfr[4];
    #pragma unroll
    for (int mi = 0; mi < 2; ++mi)
      af[mi] = *(const f16x8*)&Al[lg * 512 + (wm + mi * 16 + lr) * 8];
    #pragma unroll
    for (int ni = 0; ni < 4; ++ni)
      bfr[ni] = *(const f16x8*)&Bl[lg][wn + ni * 16 + lr][0];
    #pragma unroll
    for (int mi = 0; mi < 2; ++mi)
      #pragma unroll
      for (int ni = 0; ni < 4; ++ni)
        acc[mi][ni] = __builtin_amdgcn_mfma_f32_16x16x32_f16(
            af[mi], bfr[ni], acc[mi][ni], 0, 0, 0);
  }
  // epilogue: val = silu(gate) * acc -> fp16 image [mp][kt][kb][m][j], K=N
  const size_t pimg = (size_t)(N >> 5) * 2048;
  #pragma unroll
  for (int mi = 0; mi < 2; ++mi) {
    #pragma unroll
    for (int ni = 0; ni < 4; ++ni) {
      const int rr = m0 + wm + mi * 16 + lg * 4;
      const int cc = n0 + wn + ni * 16 + lr;
      #pragma unroll
      for (int r2 = 0; r2 < 4; ++r2) {
        int row = rr + r2;
        float gv = gate[(size_t)row * N + cc];
        float val = acc[mi][ni][r2] * (gv / (1.f + expf(-gv)));
        float nb = __shfl_down(val, 1, 64);
        if (!(lr & 1)) {
          int kt = cc >> 5, kb2 = (cc >> 3) & 3, j2 = cc & 7;
          int m = row & 63, mp = row >> 6;
          *(unsigned int*)(out16 + (size_t)mp * pimg + (size_t)kt * 2048
                           + kb2 * 512 + m * 8 + j2) = pack2h(val, nb);
        }
      }
    }
  }
}

// =================================================================
// gemm_f16: both operands f32, reg-converted (lm_head fallback only)
// =================================================================
template<int TM, bool ACC, bool FS>
__global__ __launch_bounds__(256) void gemm_f16(const float* __restrict__ A,
    const float* A2, const float* __restrict__ B,
    float* __restrict__ C, int M, int N, int K) {
  constexpr int MI = TM / 32;
  constexpr int AF = TM / 8;
  __shared__ unsigned int Al[4][TM][4];
  __shared__ unsigned int Bl[4][128][4];
  const int tid = threadIdx.x;
  const int gm = M / TM;
  const int nwg = gridDim.x;
  const int q = nwg >> 3, r = nwg & 7;
  const int xcd = blockIdx.x & 7, ii = blockIdx.x >> 3;
  const int lin = (xcd < r) ? (xcd * (q + 1) + ii)
                            : (r * (q + 1) + (xcd - r) * q + ii);
  const int m0 = (lin % gm) * TM;
  const int n0 = (lin / gm) * 128;
  const int wave = tid >> 6, lane = tid & 63;
  const int wm = (wave >> 1) * (TM / 2), wn = (wave & 1) * 64;
  const int lr = lane & 15, lg = lane >> 4;
  const int am  = (TM == 128) ? (tid >> 1) : (tid >> 2);
  const int akb = (TM == 128) ? ((tid & 1) * 2) : (tid & 3);
  const int bn = tid & 127, bkb = (tid >> 7) * 2;
  const float* Ap  = A + (size_t)(m0 + am) * K + akb * 8;
  const float* A2p = A2 + (size_t)(m0 + am) * K + akb * 8;
  const float* Bp = B + (size_t)(bkb * 8) * N + n0 + bn;
  float ar[AF], ar2[FS ? AF : 1], br[16];
  f32x4v acc[MI][4];
  #pragma unroll
  for (int i = 0; i < MI; ++i)
    #pragma unroll
    for (int j = 0; j < 4; ++j)
      #pragma unroll
      for (int r2 = 0; r2 < 4; ++r2) acc[i][j][r2] = 0.f;
  const int NT = K >> 5;
  #pragma unroll
  for (int q2 = 0; q2 < AF / 4; ++q2)
    *(float4*)&ar[q2 * 4] = *(const float4*)(Ap + q2 * 4);
  if (FS) {
    #pragma unroll
    for (int q2 = 0; q2 < AF / 4; ++q2)
      *(float4*)&ar2[q2 * 4] = *(const float4*)(A2p + q2 * 4);
  }
  #pragma unroll
  for (int j = 0; j < 16; ++j) br[j] = Bp[(size_t)j * N];
  for (int t = 0; t < NT; ++t) {
    __syncthreads();
    float av[AF];
    #pragma unroll
    for (int u = 0; u < AF; ++u) {
      float g = ar[u];
      av[u] = FS ? (g / (1.f + expf(-g))) * ar2[u] : g;
    }
    *(uint4*)&Al[akb][am][0] = make_uint4(
        pack2h(av[0], av[1]), pack2h(av[2], av[3]),
        pack2h(av[4], av[5]), pack2h(av[6], av[7]));
    if (TM == 128) {
      *(uint4*)&Al[akb + 1][am][0] = make_uint4(
          pack2h(av[8], av[9]), pack2h(av[10], av[11]),
          pack2h(av[12], av[13]), pack2h(av[14], av[15]));
    }
    *(uint4*)&Bl[bkb][bn][0] = make_uint4(
        pack2h(br[0], br[1]), pack2h(br[2], br[3]),
        pack2h(br[4], br[5]), pack2h(br[6], br[7]));
    *(uint4*)&Bl[bkb + 1][bn][0] = make_uint4(
        pack2h(br[8], br[9]), pack2h(br[10], br[11]),
        pack2h(br[12], br[13]), pack2h(br[14], br[15]));
    if (t + 1 < NT) {
      Ap += 32; A2p += 32; Bp += (size_t)32 * N;
      #pragma unroll
      for (int q2 = 0; q2 < AF / 4; ++q2)
        *(float4*)&ar[q2 * 4] = *(const float4*)(Ap + q2 * 4);
      if (FS) {
        #pragma unroll
        for (int q2 = 0; q2 < AF / 4; ++q2)
          *(float4*)&ar2[q2 * 4] = *(const float4*)(A2p + q2 * 4);
      }
      #pragma unroll
      for (int j = 0; j < 16; ++j) br[j] = Bp[(size_t)j * N];
    }
    __syncthreads();
    f16x8 af[MI], bfr[4];
    #pragma unroll
    for (int mi = 0; mi < MI; ++mi)
      af[mi] = *(const f16x8*)&Al[lg][wm + mi * 16 + lr][0];
    #pragma unroll
    for (int ni = 0; ni < 4; ++ni)
      bfr[ni] = *(const f16x8*)&Bl[lg][wn + ni * 16 + lr][0];
    #pragma unroll
    for (int mi = 0; mi < MI; ++mi)
      #pragma unroll
      for (int ni = 0; ni < 4; ++ni)
        acc[mi][ni] = __builtin_amdgcn_mfma_f32_16x16x32_f16(
            af[mi], bfr[ni], acc[mi][ni], 0, 0, 0);
  }
  #pragma unroll
  for (int mi = 0; mi < MI; ++mi) {
    #pragma unroll
    for (int ni = 0; ni < 4; ++ni) {
      const int rr = m0 + wm + mi * 16 + lg * 4;
      const int cc = n0 + wn + ni * 16 + lr;
      #pragma unroll
      for (int r2 = 0; r2 < 4; ++r2) {
        float* cp = C + (size_t)(rr + r2) * N + cc;
        if (ACC) *cp += acc[mi][ni][r2];
        else     *cp = acc[mi][ni][r2];
      }
    }
  }
}

// =================================================================
// embedding gather
// =================================================================
__global__ __launch_bounds__(256) void embed_k(const int* __restrict__ ids,
    const float* __restrict__ emb, float* __restrict__ hid) {
  int t = blockIdx.x * 256 + threadIdx.x;
  int s = t >> 9;
  int c4 = (t & 511) * 4;
  *(float4*)(hid + (size_t)s * HIDN + c4) =
      *(const float4*)(emb + (size_t)ids[s] * HIDN + c4);
}

// =================================================================
// rmsnorm over HIDN=2048; also emits fp16 A-image [mp64][kt][kb][m][j]
// =================================================================
__global__ __launch_bounds__(256) void rmsnorm_k(const float* __restrict__ in,
    const float* __restrict__ w, float* __restrict__ out,
    ushort_t* __restrict__ x16) {
  const int row = blockIdx.x;
  const float* ip = in + (size_t)row * HIDN;
  float ss = 0.f;
  for (int c = threadIdx.x * 4; c < HIDN; c += 1024) {
    float4 v = *(const float4*)(ip + c);
    ss += v.x * v.x + v.y * v.y + v.z * v.z + v.w * v.w;
  }
  #pragma unroll
  for (int o = 32; o > 0; o >>= 1) ss += __shfl_down(ss, o, 64);
  __shared__ float sred[4];
  if ((threadIdx.x & 63) == 0) sred[threadIdx.x >> 6] = ss;
  __syncthreads();
  float tot = sred[0] + sred[1] + sred[2] + sred[3];
  float sc = 1.f / sqrtf(tot * (1.f / HIDN) + 1e-6f);
  const int m = row & 63, mp = row >> 6;
  ushort_t* xb = x16 + (size_t)mp * (HIDN >> 5) * 2048 + m * 8;
  for (int c = threadIdx.x * 4; c < HIDN; c += 1024) {
    float4 v = *(const float4*)(ip + c);
    float4 o = make_float4(v.x * sc * w[c], v.y * sc * w[c + 1],
                           v.z * sc * w[c + 2], v.w * sc * w[c + 3]);
    *(float4*)(out + (size_t)row * HIDN + c) = o;
    int kt = c >> 5, kb = (c >> 3) & 3, j = c & 7;
    *(uint2*)(xb + (size_t)kt * 2048 + kb * 512 + j) =
        make_uint2(pack2h(o.x, o.y), pack2h(o.z, o.w));
  }
}

// =================================================================
// new_conv = last 4 time rows of mixed (raw, pre-silu), [c][kk]
// =================================================================
__global__ __launch_bounds__(256) void newconv_k(const float* __restrict__ mixed,
                                                 float* __restrict__ nc) {
  int t = blockIdx.x * 256 + threadIdx.x;
  int c = t >> 2, kk = t & 3;
  nc[t] = mixed[(size_t)(1020 + kk) * CDIM + c];
}

// =================================================================
// causal conv (K=4) + silu
// =================================================================
__global__ __launch_bounds__(256) void conv_k(const float* __restrict__ mixed,
    const float* __restrict__ cstate, const float* __restrict__ cw,
    const float* __restrict__ cb, float* __restrict__ convo) {
  int idx = blockIdx.x * 256 + threadIdx.x;
  int c = idx & (CDIM - 1);
  int s = idx >> 12;
  float acc = cb[c];
  #pragma unroll
  for (int kk = 0; kk < 4; ++kk) {
    int j = s + 1 + kk;
    float pv = (j < 4) ? cstate[c * 4 + j] : mixed[(size_t)(j - 4) * CDIM + c];
    acc = fmaf(cw[c * 4 + kk], pv, acc);
  }
  convo[(size_t)s * CDIM + c] = acc / (1.f + expf(-acc));
}

// =================================================================
// delta q/k L2-normalize; layout out: [h8][s][128]
// =================================================================
__global__ __launch_bounds__(128) void qknorm_k(const float* __restrict__ convo,
    float* __restrict__ qn, float* __restrict__ kn) {
  const int b = blockIdx.x;
  const int h8 = b & 7, s = b >> 3;
  const int d = threadIdx.x;
  float qv = convo[(size_t)s * CDIM + h8 * 128 + d];
  float kv = convo[(size_t)s * CDIM + 1024 + h8 * 128 + d];
  __shared__ float sred[4];
  float pq = qv * qv, pk = kv * kv;
  #pragma unroll
  for (int o = 32; o > 0; o >>= 1) { pq += __shfl_down(pq, o, 64); pk += __shfl_down(pk, o, 64); }
  if ((d & 63) == 0) { sred[d >> 6] = pq; sred[2 + (d >> 6)] = pk; }
  __syncthreads();
  float sq = sred[0] + sred[1], sk = sred[2] + sred[3];
  qn[((size_t)h8 * S_LEN + s) * 128 + d] = qv * (1.f / sqrtf(sq + 1e-6f)) * 0.08838834764831845f;
  kn[((size_t)h8 * S_LEN + s) * 128 + d] = kv * (1.f / sqrtf(sk + 1e-6f));
}

// =================================================================
// beta = sigmoid(x@b_w), g = -exp(A_log)*softplus(x@a_w + dt_bias)
// =================================================================
__global__ __launch_bounds__(256) void betag_k(const float* __restrict__ x,
    const float* __restrict__ bw, const float* __restrict__ aw,
    const float* __restrict__ A_log, const float* __restrict__ dt_bias,
    float* __restrict__ beta, float* __restrict__ g) {
  __shared__ float sx[2048];
  __shared__ float rb[16][17], ra[16][17];
  const int s = blockIdx.x;
  for (int c = threadIdx.x; c < HIDN; c += 256) sx[c] = x[(size_t)s * HIDN + c];
  __syncthreads();
  const int h = threadIdx.x & 15, part = threadIdx.x >> 4;
  float accb = 0.f, acca = 0.f;
  for (int j = 0; j < 128; ++j) {
    int k = part * 128 + j;
    float xv = sx[k];
    accb = fmaf(xv, bw[(size_t)k * 16 + h], accb);
    acca = fmaf(xv, aw[(size_t)k * 16 + h], acca);
  }
  rb[part][h] = accb; ra[part][h] = acca;
  __syncthreads();
  if (threadIdx.x < 16) {
    const int hh = threadIdx.x;
    float sb = 0.f, sa = 0.f;
    for (int p = 0; p < 16; ++p) { sb += rb[p][hh]; sa += ra[p][hh]; }
    beta[(size_t)s * 16 + hh] = 1.f / (1.f + expf(-sb));
    float aa = sa + dt_bias[hh];
    float sp = (aa > 20.f) ? aa : log1pf(expf(aa));
    g[(size_t)s * 16 + hh] = -expf(A_log[hh]) * sp;
  }
}

// =================================================================
// delta phase 1
// =================================================================
__global__ __launch_bounds__(256) void delta_phase1(
    const float* __restrict__ qn, const float* __restrict__ kn,
    const float* __restrict__ convo, const float* __restrict__ beta,
    const float* __restrict__ g,
    float* __restrict__ Wb, ushort_t* __restrict__ KC16,
    ushort_t* __restrict__ Q16, ushort_t* __restrict__ K16,
    ushort_t* __restrict__ ATT16, float* __restrict__ GCb) {
  __shared__ float sK[64][129];
  __shared__ float sV[64][129];
  __shared__ float sQ[64][129];
  __shared__ float sT[64][64];
  __shared__ float sgc[64], sbeta[64], seg[64], sEgl[64];
  const int blk = blockIdx.x;
  const int n = blk & 15, h = blk >> 4;
  const int hq = h >> 1;
  const int r0 = n * 64;
  const int tid = threadIdx.x;
  const size_t hn = (size_t)h * 16 + n;
  for (int t = tid; t < 2048; t += 256) {
    int i = t >> 5, c4 = (t & 31) * 4;
    float4 kv = *(const float4*)(kn + ((size_t)hq * S_LEN + r0 + i) * 128 + c4);
    float4 qv = *(const float4*)(qn + ((size_t)hq * S_LEN + r0 + i) * 128 + c4);
    float4 vv = *(const float4*)(convo + (size_t)(r0 + i) * CDIM + 2048 + h * 128 + c4);
    sK[i][c4+0]=kv.x; sK[i][c4+1]=kv.y; sK[i][c4+2]=kv.z; sK[i][c4+3]=kv.w;
    sQ[i][c4+0]=qv.x; sQ[i][c4+1]=qv.y; sQ[i][c4+2]=qv.z; sQ[i][c4+3]=qv.w;
    sV[i][c4+0]=vv.x; sV[i][c4+1]=vv.y; sV[i][c4+2]=vv.z; sV[i][c4+3]=vv.w;
  }
  if (tid < 64) sbeta[tid] = beta[(size_t)(r0 + tid) * NVH + h];
  __syncthreads();
  if (tid == 0) {
    float acc = 0.f;
    for (int i = 0; i < 64; ++i) { acc += g[(size_t)(r0 + i) * NVH + h]; sgc[i] = acc; }
  }
  __syncthreads();
  if (tid < 64) {
    seg[tid] = expf(sgc[tid]);
    sEgl[tid] = expf(sgc[63] - sgc[tid]);
  }
  {
    const int ty = tid >> 4, tx = tid & 15;
    float a[4][4] = {};
    #pragma unroll 4
    for (int k = 0; k < 128; ++k) {
      float kr[4], kc_[4];
      #pragma unroll
      for (int di = 0; di < 4; ++di) kr[di] = sK[ty * 4 + di][k];
      #pragma unroll
      for (int dj = 0; dj < 4; ++dj) kc_[dj] = sK[tx * 4 + dj][k];
      #pragma unroll
      for (int di = 0; di < 4; ++di)
        #pragma unroll
        for (int dj = 0; dj < 4; ++dj)
          a[di][dj] = fmaf(kr[di], kc_[dj], a[di][dj]);
    }
    #pragma unroll
    for (int di = 0; di < 4; ++di) {
      int i = ty * 4 + di;
      #pragma unroll
      for (int dj = 0; dj < 4; ++dj) {
        int j = tx * 4 + dj;
        float v;
        if (i > j) v = sbeta[i] * a[di][dj] * expf(sgc[i] - sgc[j]);
        else v = (i == j) ? 1.f : 0.f;
        sT[i][j] = v;
      }
    }
  }
  __syncthreads();
  if (tid < 64) {
    const int c = tid;
    for (int i = 1; i < 64; ++i) {
      if (c <= i) {
        float acc = (c == i) ? 1.f : 0.f;
        for (int j = c; j < i; ++j) acc -= sT[i][j] * sT[j][c];
        sT[i][c] = acc;
      }
    }
  }
  __syncthreads();
  for (int t = tid; t < 1024; t += 256) {
    int i = t >> 4, dg = (t & 15) * 8;
    float aw[8] = {}, ak[8] = {};
    for (int j = 0; j <= i; ++j) {
      float tv = sT[i][j] * sbeta[j];
      float te = tv * seg[j];
      #pragma unroll
      for (int u = 0; u < 8; ++u) {
        aw[u] = fmaf(tv, sV[j][dg + u], aw[u]);
        ak[u] = fmaf(te, sK[j][dg + u], ak[u]);
      }
    }
    float* wp = Wb + (hn * 64 + i) * 128 + dg;
    *(float4*)wp = make_float4(aw[0], aw[1], aw[2], aw[3]);
    *(float4*)(wp + 4) = make_float4(aw[4], aw[5], aw[6], aw[7]);
    uint4 kc = make_uint4(pack2h(-ak[0], -ak[1]), pack2h(-ak[2], -ak[3]),
                          pack2h(-ak[4], -ak[5]), pack2h(-ak[6], -ak[7]));
    *(uint4*)(KC16 + hn * 8192 + (dg >> 3) * 512 + i * 8) = kc;
  }
  for (int t = tid; t < 1024; t += 256) {
    int i = t >> 4, dg = (t & 15) * 8;
    float e = seg[i];
    uint4 qv = make_uint4(
        pack2h(sQ[i][dg] * e, sQ[i][dg + 1] * e),
        pack2h(sQ[i][dg + 2] * e, sQ[i][dg + 3] * e),
        pack2h(sQ[i][dg + 4] * e, sQ[i][dg + 5] * e),
        pack2h(sQ[i][dg + 6] * e, sQ[i][dg + 7] * e));
    *(uint4*)(Q16 + hn * 8192 + (dg >> 3) * 512 + i * 8) = qv;
  }
  for (int t = tid; t < 1024; t += 256) {
    int kv = t & 127, ib = t >> 7;
    int i0 = ib * 8;
    uint4 kk2 = make_uint4(
        pack2h(sK[i0 + 0][kv] * sEgl[i0 + 0], sK[i0 + 1][kv] * sEgl[i0 + 1]),
        pack2h(sK[i0 + 2][kv] * sEgl[i0 + 2], sK[i0 + 3][kv] * sEgl[i0 + 3]),
        pack2h(sK[i0 + 4][kv] * sEgl[i0 + 4], sK[i0 + 5][kv] * sEgl[i0 + 5]),
        pack2h(sK[i0 + 6][kv] * sEgl[i0 + 6], sK[i0 + 7][kv] * sEgl[i0 + 7]));
    *(uint4*)(K16 + hn * 8192 + ib * 1024 + kv * 8) = kk2;
  }
  __syncthreads();
  {
    const int ty = tid >> 4, tx = tid & 15;
    float a[4][4] = {};
    #pragma unroll 4
    for (int k = 0; k < 128; ++k) {
      float qr[4], kc_[4];
      #pragma unroll
      for (int di = 0; di < 4; ++di) qr[di] = sQ[ty * 4 + di][k];
      #pragma unroll
      for (int dj = 0; dj < 4; ++dj) kc_[dj] = sK[tx * 4 + dj][k];
      #pragma unroll
      for (int di = 0; di < 4; ++di)
        #pragma unroll
        for (int dj = 0; dj < 4; ++dj)
          a[di][dj] = fmaf(qr[di], kc_[dj], a[di][dj]);
    }
    #pragma unroll
    for (int di = 0; di < 4; ++di) {
      int i = ty * 4 + di;
      #pragma unroll
      for (int dj = 0; dj < 4; ++dj) {
        int j = tx * 4 + dj;
        float v = 0.f;
        if (i >= j) v = a[di][dj] * expf(sgc[i] - sgc[j]);
        sT[i][j] = v;
      }
    }
  }
  __syncthreads();
  for (int t = tid; t < 512; t += 256) {
    int i = t >> 3, jb = t & 7;
    const float* ap = &sT[i][jb * 8];
    uint4 av = make_uint4(pack2h(ap[0], ap[1]), pack2h(ap[2], ap[3]),
                          pack2h(ap[4], ap[5]), pack2h(ap[6], ap[7]));
    *(uint4*)(ATT16 + hn * 4096 + jb * 512 + i * 8) = av;
  }
  if (tid < 64) GCb[hn * 64 + tid] = sgc[tid];
}

// =================================================================
// delta phase 2 (MFMA): state in accumulators across 16 chunks
// =================================================================
__global__ __launch_bounds__(256) void delta_phase2(
    const ushort_t* __restrict__ KC16, const ushort_t* __restrict__ Q16,
    const ushort_t* __restrict__ K16, const ushort_t* __restrict__ ATT16,
    const float* __restrict__ Wb, const float* __restrict__ GCb,
    const float* __restrict__ rec_state,
    float* __restrict__ core, float* __restrict__ new_rec) {
  __shared__ uint4 bufKC[1024];
  __shared__ uint4 bufQ[1024];
  __shared__ uint4 bufK[1024];
  __shared__ uint4 bufA[512];
  __shared__ uint4 bufS[512];
  __shared__ uint4 bufV[256];
  ushort_t* sKC = (ushort_t*)bufKC;
  ushort_t* sQ6 = (ushort_t*)bufQ;
  ushort_t* sK6 = (ushort_t*)bufK;
  ushort_t* sAT = (ushort_t*)bufA;
  ushort_t* sS  = (ushort_t*)bufS;
  ushort_t* sVn = (ushort_t*)bufV;
  const int h = blockIdx.x >> 2, ds = blockIdx.x & 3;
  const int d0 = ds * 32;
  const int tid = threadIdx.x;
  const int w = tid >> 6;
  const int lane = tid & 63, lr = lane & 15, lg = lane >> 4;
  const int rowS0 = w * 32;
  f32x4v aS[2][2];
  #pragma unroll
  for (int tm = 0; tm < 2; ++tm)
    #pragma unroll
    for (int tn = 0; tn < 2; ++tn)
      #pragma unroll
      for (int r = 0; r < 4; ++r) {
        int row = rowS0 + tm * 16 + lg * 4 + r;
        int col = tn * 16 + lr;
        aS[tm][tn][r] = rec_state[((size_t)h * 128 + row) * 128 + d0 + col];
      }
  for (int n = 0; n < 16; ++n) {
    const size_t hn = (size_t)h * 16 + n;
    const uint4* pKC = (const uint4*)(KC16 + hn * 8192);
    const uint4* pQ  = (const uint4*)(Q16  + hn * 8192);
    const uint4* pK  = (const uint4*)(K16  + hn * 8192);
    const uint4* pA  = (const uint4*)(ATT16 + hn * 4096);
    uint4 stKC[4], stQ[4], stK[4], stA[2];
    #pragma unroll
    for (int u = 0; u < 4; ++u) {
      stKC[u] = pKC[tid + u * 256];
      stQ[u]  = pQ[tid + u * 256];
      stK[u]  = pK[tid + u * 256];
    }
    #pragma unroll
    for (int u = 0; u < 2; ++u) stA[u] = pA[tid + u * 256];
    const float egl = expf(GCb[hn * 64 + 63]);
    float wseed[2][4];
    #pragma unroll
    for (int tn = 0; tn < 2; ++tn)
      #pragma unroll
      for (int r = 0; r < 4; ++r)
        wseed[tn][r] = Wb[(hn * 64 + (w * 16 + lg * 4 + r)) * 128 + d0 + tn * 16 + lr];
    #pragma unroll
    for (int tm = 0; tm < 2; ++tm)
      #pragma unroll
      for (int tn = 0; tn < 2; ++tn)
        #pragma unroll
        for (int r = 0; r < 4; ++r) {
          int row = rowS0 + tm * 16 + lg * 4 + r;
          int col = tn * 16 + lr;
          sS[(row >> 3) * 256 + col * 8 + (row & 7)] = h16(aS[tm][tn][r]);
        }
    #pragma unroll
    for (int u = 0; u < 4; ++u) {
      bufKC[tid + u * 256] = stKC[u];
      bufQ[tid + u * 256]  = stQ[u];
      bufK[tid + u * 256]  = stK[u];
    }
    #pragma unroll
    for (int u = 0; u < 2; ++u) bufA[tid + u * 256] = stA[u];
    __syncthreads();
    f32x4v aV[2];
    #pragma unroll
    for (int tn = 0; tn < 2; ++tn)
      #pragma unroll
      for (int r = 0; r < 4; ++r) aV[tn][r] = wseed[tn][r];
    #pragma unroll
    for (int c = 0; c < 4; ++c) {
      f16x8 a = *(const f16x8*)&sKC[((c * 4 + lg) * 64 + w * 16 + lr) * 8];
      #pragma unroll
      for (int tn = 0; tn < 2; ++tn) {
        f16x8 b = *(const f16x8*)&sS[((c * 4 + lg) * 32 + tn * 16 + lr) * 8];
        aV[tn] = __builtin_amdgcn_mfma_f32_16x16x32_f16(a, b, aV[tn], 0, 0, 0);
      }
    }
    #pragma unroll
    for (int tn = 0; tn < 2; ++tn)
      #pragma unroll
      for (int r = 0; r < 4; ++r) {
        int row = w * 16 + lg * 4 + r;
        int col = tn * 16 + lr;
        sVn[(row >> 3) * 256 + col * 8 + (row & 7)] = h16(aV[tn][r]);
      }
    __syncthreads();
    f32x4v aO[2];
    #pragma unroll
    for (int tn = 0; tn < 2; ++tn)
      #pragma unroll
      for (int r = 0; r < 4; ++r) aO[tn][r] = 0.f;
    #pragma unroll
    for (int c = 0; c < 4; ++c) {
      f16x8 a = *(const f16x8*)&sQ6[((c * 4 + lg) * 64 + w * 16 + lr) * 8];
      #pragma unroll
      for (int tn = 0; tn < 2; ++tn) {
        f16x8 b = *(const f16x8*)&sS[((c * 4 + lg) * 32 + tn * 16 + lr) * 8];
        aO[tn] = __builtin_amdgcn_mfma_f32_16x16x32_f16(a, b, aO[tn], 0, 0, 0);
      }
    }
    #pragma unroll
    for (int c = 0; c < 2; ++c) {
      f16x8 a = *(const f16x8*)&sAT[((c * 4 + lg) * 64 + w * 16 + lr) * 8];
      #pragma unroll
      for (int tn = 0; tn < 2; ++tn) {
        f16x8 b = *(const f16x8*)&sVn[((c * 4 + lg) * 32 + tn * 16 + lr) * 8];
        aO[tn] = __builtin_amdgcn_mfma_f32_16x16x32_f16(a, b, aO[tn], 0, 0, 0);
      }
    }
    #pragma unroll
    for (int tn = 0; tn < 2; ++tn)
      #pragma unroll
      for (int r = 0; r < 4; ++r) {
        int row = w * 16 + lg * 4 + r;
        core[(size_t)(n * 64 + row) * HIDN + h * 128 + d0 + tn * 16 + lr] = aO[tn][r];
      }
    #pragma unroll
    for (int tm = 0; tm < 2; ++tm)
      #pragma unroll
      for (int tn = 0; tn < 2; ++tn)
        #pragma unroll
        for (int r = 0; r < 4; ++r) aS[tm][tn][r] *= egl;
    #pragma unroll
    for (int tm = 0; tm < 2; ++tm) {
      #pragma unroll
      for (int c = 0; c < 2; ++c) {
        f16x8 a = *(const f16x8*)&sK6[((c * 4 + lg) * 128 + rowS0 + tm * 16 + lr) * 8];
        #pragma unroll
        for (int tn = 0; tn < 2; ++tn) {
          f16x8 b = *(const f16x8*)&sVn[((c * 4 + lg) * 32 + tn * 16 + lr) * 8];
          aS[tm][tn] = __builtin_amdgcn_mfma_f32_16x16x32_f16(a, b, aS[tm][tn], 0, 0, 0);
        }
      }
    }
    __syncthreads();
  }
  #pragma unroll
  for (int tm = 0; tm < 2; ++tm)
    #pragma unroll
    for (int tn = 0; tn < 2; ++tn)
      #pragma unroll
      for (int r = 0; r < 4; ++r) {
        int row = rowS0 + tm * 16 + lg * 4 + r;
        int col = tn * 16 + lr;
        new_rec[((size_t)h * 128 + row) * 128 + d0 + col] = aS[tm][tn][r];
      }
}

// =================================================================
// gated rmsnorm over DV=128 rows -> fp16 A-image only
// =================================================================
__global__ __launch_bounds__(128) void gatedrms_k(const float* __restrict__ core,
    const float* __restrict__ z, const float* __restrict__ w,
    ushort_t* __restrict__ c16) {
  const int b = blockIdx.x;
  const int h = b & 15, s = b >> 4;
  const int d = threadIdx.x;
  size_t idx = (size_t)s * HIDN + h * 128 + d;
  float cv = core[idx], zv = z[idx];
  float xf = cv * (zv / (1.f + expf(-zv)));
  __shared__ float sred[2];
  float ps = xf * xf;
  #pragma unroll
  for (int o = 32; o > 0; o >>= 1) ps += __shfl_down(ps, o, 64);
  if ((d & 63) == 0) sred[d >> 6] = ps;
  __syncthreads();
  float ss = sred[0] + sred[1];
  float val = xf * (1.f / sqrtf(ss * (1.f / 128.f) + 1e-6f)) * w[d];
  float nb = __shfl_down(val, 1, 64);
  if (!(d & 1)) {
    int c = h * 128 + d;
    int kt = c >> 5, kb = (c >> 3) & 3, j = c & 7;
    int m = s & 63, mp = s >> 6;
    *(unsigned int*)(c16 + (size_t)mp * 131072 + kt * 2048 + kb * 512 + m * 8 + j)
        = pack2h(val, nb);
  }
}

// =================================================================
// attention q: rmsnorm(q_norm_w) + rope; also extract gate
// =================================================================
__global__ __launch_bounds__(128) void qrope_k(const float* __restrict__ qg,
    const float* __restrict__ qnw, const float* __restrict__ cosb,
    const float* __restrict__ sinb, float* __restrict__ qhat,
    float* __restrict__ agate) {
  const int b = blockIdx.x;
  const int h = b & 15, s = b >> 4;
  const int d = threadIdx.x;
  float qv = qg[(size_t)s * 4096 + h * 256 + d];
  float gv = qg[(size_t)s * 4096 + h * 256 + 128 + d];
  __shared__ float sred[2];
  float ps = qv * qv;
  #pragma unroll
  for (int o = 32; o > 0; o >>= 1) ps += __shfl_down(ps, o, 64);
  if ((d & 63) == 0) sred[d >> 6] = ps;
  __syncthreads();
  float ss = sred[0] + sred[1];
  float qn_ = qv * (1.f / sqrtf(ss * (1.f / 128.f) + 1e-6f)) * qnw[d];
  __shared__ float tmp[128];
  tmp[d] = qn_;
  __syncthreads();
  float other = tmp[d ^ 64];
  float rh = (d < 64) ? -other : other;
  float c = cosb[(size_t)s * 128 + d];
  float sn = sinb[(size_t)s * 128 + d];
  qhat[((size_t)h * S_LEN + s) * 128 + d] = qn_ * c + rh * sn;
  agate[(size_t)s * HIDN + h * 128 + d] = gv;
}

// =================================================================
// attention k: rmsnorm + rope -> kcache rows SP..; v -> vcache
// =================================================================
__global__ __launch_bounds__(128) void kvrope_k(const float* __restrict__ kraw,
    const float* __restrict__ vraw, const float* __restrict__ knw,
    const float* __restrict__ cosb, const float* __restrict__ sinb,
    float* __restrict__ kcache, float* __restrict__ vcache) {
  const int b = blockIdx.x;
  const int h2 = b & 1, s = b >> 1;
  const int d = threadIdx.x;
  float kv = kraw[(size_t)s * 256 + h2 * 128 + d];
  __shared__ float sred[2];
  float ps = kv * kv;
  #pragma unroll
  for (int o = 32; o > 0; o >>= 1) ps += __shfl_down(ps, o, 64);
  if ((d & 63) == 0) sred[d >> 6] = ps;
  __syncthreads();
  float ss = sred[0] + sred[1];
  float kn_ = kv * (1.f / sqrtf(ss * (1.f / 128.f) + 1e-6f)) * knw[d];
  __shared__ float tmp[128];
  tmp[d] = kn_;
  __syncthreads();
  float other = tmp[d ^ 64];
  float rh = (d < 64) ? -other : other;
  size_t row = (size_t)h2 * MAXKV + SP + s;
  kcache[row * 128 + d] = kn_ * cosb[(size_t)s * 128 + d] + rh * sinb[(size_t)s * 128 + d];
  vcache[row * 128 + d] = vraw[(size_t)s * 256 + h2 * 128 + d];
}

// =================================================================
// KV cache -> fp16 pre-swizzled tiles for attn (rows 0..1535)
// =================================================================
__global__ __launch_bounds__(256) void kv16_k(const float* __restrict__ kc,
    const float* __restrict__ vc, ushort_t* __restrict__ KV16) {
  const int b = blockIdx.x;            // 48 blocks
  const int kt = b % 24, h2 = b / 24;
  const int tid = threadIdx.x;
  const float* Kb = kc + ((size_t)h2 * MAXKV + kt * 64) * 128;
  const float* Vb = vc + ((size_t)h2 * MAXKV + kt * 64) * 128;
  ushort_t* Ko = KV16 + ((size_t)h2 * 24 + kt) * 8192;
  ushort_t* Vo = KV16 + 393216 + ((size_t)h2 * 24 + kt) * 8192;
  #pragma unroll
  for (int it = 0; it < 4; ++it) {
    int tt = tid + it * 256;
    int row = tt >> 4, kb = tt & 15;
    float4 a = *(const float4*)(Kb + row * 128 + kb * 8);
    float4 c = *(const float4*)(Kb + row * 128 + kb * 8 + 4);
    *(uint4*)(Ko + ((size_t)kb * 64 + row) * 8) = make_uint4(
        pack2h(a.x, a.y), pack2h(a.z, a.w), pack2h(c.x, c.y), pack2h(c.z, c.w));
  }
  #pragma unroll
  for (int it = 0; it < 4; ++it) {
    int tt = tid + it * 256;
    int key = tt >> 4, dg = tt & 15;
    float4 a = *(const float4*)(Vb + key * 128 + dg * 8);
    float4 c = *(const float4*)(Vb + key * 128 + dg * 8 + 4);
    int base = (key >> 3) * 1024 + (key & 7);
    Vo[base + (dg * 8 + 0) * 8] = h16(a.x);
    Vo[base + (dg * 8 + 1) * 8] = h16(a.y);
    Vo[base + (dg * 8 + 2) * 8] = h16(a.z);
    Vo[base + (dg * 8 + 3) * 8] = h16(a.w);
    Vo[base + (dg * 8 + 4) * 8] = h16(c.x);
    Vo[base + (dg * 8 + 5) * 8] = h16(c.y);
    Vo[base + (dg * 8 + 6) * 8] = h16(c.z);
    Vo[base + (dg * 8 + 7) * 8] = h16(c.w);
  }
}

// =================================================================
// fp16 MFMA flash attention; K/V via global_load_lds; fp16 A-image out
// =================================================================
__global__ __launch_bounds__(256) void attn_k(const float* __restrict__ qhat,
    const ushort_t* __restrict__ KV16,
    const float* __restrict__ agate, ushort_t* __restrict__ AO16) {
  __shared__ unsigned int Ql[16][64][4];
  __shared__ unsigned int Kl[16][64][4];
  __shared__ unsigned int Vl[8][128][4];
  __shared__ unsigned int Pl[8][64][4];
  const int h = blockIdx.x >> 4, qb = blockIdx.x & 15;
  const int hkv = h >> 3;
  const int tid = threadIdx.x;
  const int wave = tid >> 6, lane = tid & 63;
  const int lr = lane & 15, lg = lane >> 4;
  const float SCALE = 0.08838834764831845f;
  const float* Qb = qhat + ((size_t)h * S_LEN + qb * 64) * 128;
  #pragma unroll
  for (int it = 0; it < 4; ++it) {
    int tt = tid + it * 256;
    int row = tt >> 4, kb = tt & 15;
    float4 a = *(const float4*)(Qb + row * 128 + kb * 8);
    float4 b = *(const float4*)(Qb + row * 128 + kb * 8 + 4);
    *(uint4*)&Ql[kb][row][0] = make_uint4(
        pack2h(a.x * SCALE, a.y * SCALE), pack2h(a.z * SCALE, a.w * SCALE),
        pack2h(b.x * SCALE, b.y * SCALE), pack2h(b.z * SCALE, b.w * SCALE));
  }
  float m_run[4], l_run[4];
  #pragma unroll
  for (int r = 0; r < 4; ++r) { m_run[r] = -3.0e38f; l_run[r] = 0.f; }
  f32x4v accO[8];
  #pragma unroll
  for (int nd = 0; nd < 8; ++nd)
    #pragma unroll
    for (int r = 0; r < 4; ++r) accO[nd][r] = 0.f;
  const int ntiles = 9 + qb;
  for (int kt = 0; kt < ntiles; ++kt) {
    __syncthreads();
    const ushort_t* Ks = KV16 + ((size_t)hkv * 24 + kt) * 8192;
    const ushort_t* Vs = KV16 + 393216 + ((size_t)hkv * 24 + kt) * 8192;
    #pragma unroll
    for (int i2 = 0; i2 < 4; ++i2) {
      int c = wave * 4 + i2;
      gload16(Ks + (size_t)c * 512 + lane * 8, (char*)Kl + c * 1024);
      gload16(Vs + (size_t)c * 512 + lane * 8, (char*)Vl + c * 1024);
    }
    __syncthreads();
    f32x4v accS[4];
    #pragma unroll
    for (int ni = 0; ni < 4; ++ni)
      #pragma unroll
      for (int r = 0; r < 4; ++r) accS[ni][r] = 0.f;
    #pragma unroll
    for (int c = 0; c < 4; ++c) {
      f16x8 aq = *(const f16x8*)&Ql[c * 4 + lg][wave * 16 + lr][0];
      #pragma unroll
      for (int ni = 0; ni < 4; ++ni) {
        f16x8 bk = *(const f16x8*)&Kl[c * 4 + lg][ni * 16 + lr][0];
        accS[ni] = __builtin_amdgcn_mfma_f32_16x16x32_f16(aq, bk, accS[ni], 0, 0, 0);
      }
    }
    const bool boundary = (kt == ntiles - 1);
    float alpha[4];
    #pragma unroll
    for (int r = 0; r < 4; ++r) {
      const int qrow = wave * 16 + lg * 4 + r;
      float tm = -3.0e38f;
      #pragma unroll
      for (int ni = 0; ni < 4; ++ni) {
        if (boundary && (ni * 16 + lr) > qrow) accS[ni][r] = -3.0e38f;
        tm = fmaxf(tm, accS[ni][r]);
      }
      tm = fmaxf(tm, __shfl_xor(tm, 1, 64));
      tm = fmaxf(tm, __shfl_xor(tm, 2, 64));
      tm = fmaxf(tm, __shfl_xor(tm, 4, 64));
      tm = fmaxf(tm, __shfl_xor(tm, 8, 64));
      float mnew = fmaxf(m_run[r], tm);
      alpha[r] = expf(m_run[r] - mnew);
      m_run[r] = mnew;
      float ls = 0.f;
      #pragma unroll
      for (int ni = 0; ni < 4; ++ni) {
        float p = expf(accS[ni][r] - mnew);
        accS[ni][r] = p;
        ls += p;
      }
      ls += __shfl_xor(ls, 1, 64);
      ls += __shfl_xor(ls, 2, 64);
      ls += __shfl_xor(ls, 4, 64);
      ls += __shfl_xor(ls, 8, 64);
      l_run[r] = l_run[r] * alpha[r] + ls;
    }
    {
      _Float16* pp = (_Float16*)Pl;
      #pragma unroll
      for (int ni = 0; ni < 4; ++ni) {
        int key = ni * 16 + lr;
        int base = (key >> 3) * 512 + (key & 7);
        #pragma unroll
        for (int r = 0; r < 4; ++r) {
          int q = wave * 16 + lg * 4 + r;
          pp[base + q * 8] = (_Float16)accS[ni][r];
        }
      }
    }
    #pragma unroll
    for (int nd = 0; nd < 8; ++nd)
      #pragma unroll
      for (int r = 0; r < 4; ++r) accO[nd][r] *= alpha[r];
    #pragma unroll
    for (int c2 = 0; c2 < 2; ++c2) {
      f16x8 ap = *(const f16x8*)&Pl[c2 * 4 + lg][wave * 16 + lr][0];
      #pragma unroll
      for (int nd = 0; nd < 8; ++nd) {
        f16x8 bv = *(const f16x8*)&Vl[c2 * 4 + lg][nd * 16 + lr][0];
        accO[nd] = __builtin_amdgcn_mfma_f32_16x16x32_f16(ap, bv, accO[nd], 0, 0, 0);
      }
    }
  }
  #pragma unroll
  for (int r = 0; r < 4; ++r) {
    const int row = qb * 64 + wave * 16 + lg * 4 + r;
    const int m = row & 63, mp = row >> 6;
    const float inv = 1.f / l_run[r];
    #pragma unroll
    for (int nd = 0; nd < 8; ++nd) {
      int d = nd * 16 + lr;
      float gv = agate[(size_t)row * HIDN + h * 128 + d];
      float val = accO[nd][r] * inv * (1.f / (1.f + expf(-gv)));
      float nb = __shfl_down(val, 1, 64);
      if (!(lr & 1)) {
        int c = h * 128 + d;
        int kt2 = c >> 5, kb2 = (c >> 3) & 3, j2 = c & 7;
        *(unsigned int*)(AO16 + (size_t)mp * 131072 + kt2 * 2048 + kb2 * 512 + m * 8 + j2)
            = pack2h(val, nb);
      }
    }
  }
}

// =================================================================
// host
// =================================================================
static inline void gemmh128(const ushort_t* A16, const float* B, float* C,
                            int M, int N, int K, hipStream_t st) {
  dim3 g((N / 128) * (M / 128));
  hipLaunchKernelGGL((gemm_h<128, false>), g, dim3(256), 0, st, A16, B, C, M, N, K);
}
static inline void gemmh64(const ushort_t* A16, const float* B, float* C,
                           int M, int N, int K, hipStream_t st) {
  dim3 g((N / 128) * (M / 64));
  hipLaunchKernelGGL((gemm_h<64, false>), g, dim3(256), 0, st, A16, B, C, M, N, K);
}
static inline void gemmh64a(const ushort_t* A16, const float* B, float* C,
                            int M, int N, int K, hipStream_t st) {
  dim3 g((N / 128) * (M / 64));
  hipLaunchKernelGGL((gemm_h<64, true>), g, dim3(256), 0, st, A16, B, C, M, N, K);
}
static inline void gemm128(const float* A, const float* B, float* C,
                           int M, int N, int K, bool acc, hipStream_t st) {
  dim3 g((N / 128) * (M / 128));
  if (acc) hipLaunchKernelGGL((gemm_f16<128, true,  false>), g, dim3(256), 0, st, A, A, B, C, M, N, K);
  else     hipLaunchKernelGGL((gemm_f16<128, false, false>), g, dim3(256), 0, st, A, A, B, C, M, N, K);
}

extern "C" void kernel_launch(void* const* d_in, const int* in_sizes, int n_in,
                              void* d_out, int out_size, void* d_ws, size_t ws_size,
                              hipStream_t stream) {
  (void)in_sizes; (void)n_in; (void)out_size;
  const int*   ids         = (const int*)  d_in[0];
  const float* rope_cos    = (const float*)d_in[3];
  const float* rope_sin    = (const float*)d_in[4];
  const float* conv_state  = (const float*)d_in[6];
  const float* rec_state   = (const float*)d_in[7];
  const float* key_cache   = (const float*)d_in[8];
  const float* value_cache = (const float*)d_in[9];
  const float* embed_w     = (const float*)d_in[10];
  const float* dl_ln_w     = (const float*)d_in[11];
  const float* dl_qkv_w    = (const float*)d_in[12];
  const float* conv_w      = (const float*)d_in[13];
  const float* conv_b      = (const float*)d_in[14];
  const float* dl_z_w      = (const float*)d_in[15];
  const float* dl_b_w      = (const float*)d_in[16];
  const float* dl_a_w      = (const float*)d_in[17];
  const float* A_log       = (const float*)d_in[18];
  const float* dt_bias     = (const float*)d_in[19];
  const float* dn_norm_w   = (const float*)d_in[20];
  const float* dl_out_w    = (const float*)d_in[21];
  const float* dl_post_ln  = (const float*)d_in[22];
  const float* dl_gate_w   = (const float*)d_in[23];
  const float* dl_up_w     = (const float*)d_in[24];
  const float* dl_down_w   = (const float*)d_in[25];
  const float* al_ln_w     = (const float*)d_in[26];
  const float* q_w         = (const float*)d_in[27];
  const float* q_norm_w    = (const float*)d_in[28];
  const float* k_w         = (const float*)d_in[29];
  const float* k_norm_w    = (const float*)d_in[30];
  const float* v_w         = (const float*)d_in[31];
  const float* o_w         = (const float*)d_in[32];
  const float* al_post_ln  = (const float*)d_in[33];
  const float* al_gate_w   = (const float*)d_in[34];
  const float* al_up_w     = (const float*)d_in[35];
  const float* al_down_w   = (const float*)d_in[36];
  const float* final_norm  = (const float*)d_in[37];
  const float* lm_head_w   = (const float*)d_in[38];

  float* out = (float*)d_out;
  float* logits   = out;                 // 1024*32000 = 32,768,000
  float* new_conv = out + 32768000;      // 16,384
  float* new_rec  = out + 32784384;      // 262,144
  float* new_kc   = out + 33046528;      // 1,048,576
  float* new_vc   = out + 34095104;      // 1,048,576

  // scratch arena inside the logits region (fully dead before final GEMM)
  float* A_mixed = logits;               // 4,194,304
  float* A_convo = logits + 4194304;     // 4,194,304
  float* A_z     = logits + 8388608;     // 2,097,152
  float* A_qn    = logits + 10485760;    // 1,048,576
  float* A_kn    = logits + 11534336;    // 1,048,576 (CORE16 after delta)
  float* A_w     = logits + 12582912;    // 2,097,152 (Wb f32)
  float* A_kc    = logits + 14680064;    // 2,097,152 (8MB -> KC16 + K16)
  float* A_att   = logits + 16777216;    // 1,048,576 (4MB -> Q16)
  float* A_gc    = logits + 17825792;    // 16,384
  float* A_core  = logits + 17842176;    // 2,097,152
  float* A_big0  = logits + 19939328;    // 6,291,456 (ATT16 delta; gate f32 MLP; KV16 attn)
  float* A_big1  = logits + 26230784;    // 6,291,456 (HB16 MLP; qhat/gate attn)
  float* A_qhat  = A_big1;               // 2,097,152
  float* A_gate  = A_big1 + 2097152;     // 2,097,152
  float* A_kraw  = A_mixed;              // 262,144 (mixed dead by then)
  float* A_vraw  = A_mixed + 262144;     // 262,144

  ushort_t* KC16  = (ushort_t*)A_kc;             // 4MB
  ushort_t* K16   = (ushort_t*)A_kc + 2097152;   // 4MB
  ushort_t* Q16   = (ushort_t*)A_att;            // 4MB
  ushort_t* ATT16 = (ushort_t*)A_big0;           // 2MB (delta section only)
  ushort_t* KV16  = (ushort_t*)(A_big0 + 4194304); // 1.5MB (attn section only)
  ushort_t* CORE16 = (ushort_t*)A_kn;            // 4MB (post-delta; kn dead)
  ushort_t* AO16   = (ushort_t*)(A_mixed + 524288); // 4MB (post-kvrope)
  ushort_t* HB16   = (ushort_t*)A_big1;          // 12.6MB fp16 image (MLP only)

  float* ws     = (float*)d_ws;
  float* W_hid  = ws;                    // 2,097,152
  float* W_x    = ws + 2097152;          // 2,097,152
  float* W_beta = ws + 4194304;          // 16,384
  float* W_g    = ws + 4210688;          // 16,384

  const bool ws_ok = (ws_size >= (size_t)21102592 + 65536);
  ushort_t* X16 = ws_ok ? (ushort_t*)(ws + 4227072)
                        : (ushort_t*)A_qn;

  // ---- embedding + delta layer ----
  hipLaunchKernelGGL(embed_k, dim3(2048), dim3(256), 0, stream, ids, embed_w, W_hid);
  hipLaunchKernelGGL(rmsnorm_k, dim3(1024), dim3(256), 0, stream, W_hid, dl_ln_w, W_x, X16);
  gemmh128(X16, dl_qkv_w, A_mixed, 1024, 4096, 2048, stream);
  hipLaunchKernelGGL(newconv_k, dim3(64), dim3(256), 0, stream, A_mixed, new_conv);
  hipLaunchKernelGGL(conv_k, dim3(16384), dim3(256), 0, stream,
                     A_mixed, conv_state, conv_w, conv_b, A_convo);
  gemmh64(X16, dl_z_w, A_z, 1024, 2048, 2048, stream);
  hipLaunchKernelGGL(betag_k, dim3(1024), dim3(256), 0, stream,
                     W_x, dl_b_w, dl_a_w, A_log, dt_bias, W_beta, W_g);
  hipLaunchKernelGGL(qknorm_k, dim3(8192), dim3(128), 0, stream, A_convo, A_qn, A_kn);
  hipLaunchKernelGGL(delta_phase1, dim3(256), dim3(256), 0, stream,
                     A_qn, A_kn, A_convo, W_beta, W_g,
                     A_w, KC16, Q16, K16, ATT16, A_gc);
  hipLaunchKernelGGL(delta_phase2, dim3(64), dim3(256), 0, stream,
                     KC16, Q16, K16, ATT16, A_w, A_gc, rec_state, A_core, new_rec);
  hipLaunchKernelGGL(gatedrms_k, dim3(16384), dim3(128), 0, stream,
                     A_core, A_z, dn_norm_w, CORE16);
  gemmh64a(CORE16, dl_out_w, W_hid, 1024, 2048, 2048, stream);
  // ---- MLP 1: gate f32, up fused with silu(gate) -> fp16 image, down plain ----
  hipLaunchKernelGGL(rmsnorm_k, dim3(1024), dim3(256), 0, stream, W_hid, dl_post_ln, W_x, X16);
  gemmh64(X16, dl_gate_w, A_big0, 1024, 6144, 2048, stream);
  hipLaunchKernelGGL(gemm_hu, dim3((6144 / 128) * (1024 / 64)), dim3(256), 0, stream,
                     X16, dl_up_w, A_big0, HB16, 1024, 6144, 2048);
  gemmh64a(HB16, dl_down_w, W_hid, 1024, 2048, 6144, stream);
  // ---- softmax attention layer ----
  hipLaunchKernelGGL(rmsnorm_k, dim3(1024), dim3(256), 0, stream, W_hid, al_ln_w, W_x, X16);
  gemmh128(X16, q_w, A_big0, 1024, 4096, 2048, stream);
  hipLaunchKernelGGL(qrope_k, dim3(16384), dim3(128), 0, stream,
                     A_big0, q_norm_w, rope_cos, rope_sin, A_qhat, A_gate);
  gemmh64(X16, k_w, A_kraw, 1024, 256, 2048, stream);
  gemmh64(X16, v_w, A_vraw, 1024, 256, 2048, stream);
  hipMemcpyAsync(new_kc, key_cache,   (size_t)2 * MAXKV * 128 * 4, hipMemcpyDeviceToDevice, stream);
  hipMemcpyAsync(new_vc, value_cache, (size_t)2 * MAXKV * 128 * 4, hipMemcpyDeviceToDevice, stream);
  hipLaunchKernelGGL(kvrope_k, dim3(2048), dim3(128), 0, stream,
                     A_kraw, A_vraw, k_norm_w, rope_cos, rope_sin, new_kc, new_vc);
  hipLaunchKernelGGL(kv16_k, dim3(48), dim3(256), 0, stream, new_kc, new_vc, KV16);
  hipLaunchKernelGGL(attn_k, dim3(256), dim3(256), 0, stream,
                     A_qhat, KV16, A_gate, AO16);
  gemmh64a(AO16, o_w, W_hid, 1024, 2048, 2048, stream);
  // ---- MLP 2 (same fused scheme) ----
  hipLaunchKernelGGL(rmsnorm_k, dim3(1024), dim3(256), 0, stream, W_hid, al_post_ln, W_x, X16);
  gemmh64(X16, al_gate_w, A_big0, 1024, 6144, 2048, stream);
  hipLaunchKernelGGL(gemm_hu, dim3((6144 / 128) * (1024 / 64)), dim3(256), 0, stream,
                     X16, al_up_w, A_big0, HB16, 1024, 6144, 2048);
  gemmh64a(HB16, al_down_w, W_hid, 1024, 2048, 6144, stream);
  // ---- final norm + lm_head ----
  hipLaunchKernelGGL(rmsnorm_k, dim3(1024), dim3(256), 0, stream, W_hid, final_norm, W_x, X16);
  if (ws_ok) gemmh128(X16, lm_head_w, logits, 1024, LMN, 2048, stream);
  else       gemm128(W_x, lm_head_w, logits, 1024, LMN, 2048, false, stream);
}